// Round 12
// baseline (466.399 us; speedup 1.0000x reference)
//
#include <hip/hip_runtime.h>
#include <hip/hip_bf16.h>
#include <cstdio>

#define N_P   65536
#define N_E   524288
#define RIG_  4096

typedef __attribute__((ext_vector_type(8))) short bf16x8;
typedef __attribute__((ext_vector_type(4))) float f32x4;
typedef unsigned short u16;
typedef unsigned int   u32;

__device__ __forceinline__ u16 f2b(float x) {
    __hip_bfloat16 h = __float2bfloat16(x);
    return *(u16*)&h;
}
__device__ __forceinline__ float b2f(u16 u) {
    union { unsigned u; float f; } c; c.u = ((unsigned)u) << 16; return c.f;
}
__device__ __forceinline__ unsigned pk2(float x, float y) {
    return (unsigned)f2b(x) | ((unsigned)f2b(y) << 16);
}
#define MFMA(a,b,c) __builtin_amdgcn_mfma_f32_16x16x32_bf16((a),(b),(c),0,0,0)

// Frag-tile LDS index with XOR bank swizzle: logical slot (row, m) -> physical
// offset. m ^= row&7 spreads the per-row m-slots across bank groups (bank group
// was m&7 independent of row -> 8-way conflicts on staging/repack). Bijective
// per row => pure relabeling, bitwise-identical results.
__device__ __forceinline__ int FIDX(int row, int m) {
    return (row * 16 + (m ^ (row & 7))) * 8;
}

// LDS-only barrier: waits LDS ops, does NOT drain global stores/atomics.
__device__ __forceinline__ void bar_l() {
    asm volatile("s_waitcnt lgkmcnt(0)\n\ts_barrier" ::: "memory");
}

// ================= sort: histogram / scan / scatter =================
__global__ __launch_bounds__(256) void k_hist(const int* __restrict__ recv,
                                              u32* __restrict__ cnt) {
    int i = blockIdx.x * 256 + threadIdx.x;
    if (i < N_E) atomicAdd(&cnt[recv[i]], 1u);
}
__global__ __launch_bounds__(256) void k_scan1(u32* __restrict__ data,
                                               u32* __restrict__ bsum) {
    __shared__ u32 s[256];
    int t = threadIdx.x, g = blockIdx.x * 256 + t;
    u32 v = data[g];
    s[t] = v; __syncthreads();
    for (int o = 1; o < 256; o <<= 1) {
        u32 x = (t >= o) ? s[t - o] : 0u;
        __syncthreads(); s[t] += x; __syncthreads();
    }
    data[g] = s[t] - v;
    if (t == 255) bsum[blockIdx.x] = s[255];
}
__global__ __launch_bounds__(256) void k_scan2(u32* __restrict__ bsum) {
    __shared__ u32 s[256];
    int t = threadIdx.x;
    u32 v = bsum[t];
    s[t] = v; __syncthreads();
    for (int o = 1; o < 256; o <<= 1) {
        u32 x = (t >= o) ? s[t - o] : 0u;
        __syncthreads(); s[t] += x; __syncthreads();
    }
    bsum[t] = s[t] - v;
}
__global__ __launch_bounds__(256) void k_scan3(u32* __restrict__ data,
                                               const u32* __restrict__ bsum) {
    int g = blockIdx.x * 256 + threadIdx.x;
    data[g] += bsum[blockIdx.x];
}
// packed edge record: {recv, send, orig_idx, pad} -> one 16B store per edge
__global__ __launch_bounds__(256) void k_scatter(const int* __restrict__ recv,
                                                 const int* __restrict__ send,
                                                 u32* __restrict__ head,
                                                 int4* __restrict__ edges) {
    int i = blockIdx.x * 256 + threadIdx.x;
    if (i < N_E) {
        int n = recv[i];
        u32 pos = atomicAdd(&head[n], 1u);
        edges[pos] = make_int4(n, send[i], i, 0);
    }
}

// ================= fused weight conversion =================
// modes: 0 plain; 2 pad-rows [3][128]->[16][128]; 3 col-slice stride 384;
// 4 col-slice stride 256; 5 W0r-select; 6 W0s-select; 7 pad15->32
struct CvtJob { const float* src; u16* dst; int n; int mode; int bstart; };
struct CvtArgs { CvtJob j[14]; };

__global__ __launch_bounds__(256) void k_cvt_all(CvtArgs a) {
    int b = blockIdx.x;
    int ji = 0;
    #pragma unroll
    for (int k = 1; k < 14; k++) if (b >= a.j[k].bstart) ji = k;
    CvtJob jb = a.j[ji];
    int i = (b - jb.bstart) * 256 + threadIdx.x;
    if (i >= jb.n) return;
    if (jb.mode == 0) {
        jb.dst[i] = f2b(jb.src[i]);
    } else if (jb.mode == 2) {
        int r = i >> 7;
        jb.dst[i] = (r < 3) ? f2b(jb.src[i]) : 0;
    } else if (jb.mode == 3) {
        int r = i >> 7, c = i & 127;
        jb.dst[i] = f2b(jb.src[r * 384 + c]);
    } else if (jb.mode == 4) {
        int r = i >> 7, c = i & 127;
        jb.dst[i] = f2b(jb.src[r * 256 + c]);
    } else if (jb.mode == 5) {               // W0r: [attr2_r(9), state_r(6)] cols
        int r = i >> 5, c = i & 31;
        float v = 0.f;
        if (c < 9)       v = jb.src[r * 31 + c];
        else if (c < 15) v = jb.src[r * 31 + 18 + (c - 9)];
        jb.dst[i] = f2b(v);
    } else if (jb.mode == 6) {               // W0s: [attr2_s(9), state_s(6)] cols
        int r = i >> 5, c = i & 31;
        float v = 0.f;
        if (c < 9)       v = jb.src[r * 31 + 9 + c];
        else if (c < 15) v = jb.src[r * 31 + 24 + (c - 9)];
        jb.dst[i] = f2b(v);
    } else {                                  // mode 7: [128][15] -> [128][32]
        int r = i >> 5, c = i & 31;
        jb.dst[i] = (c < 15) ? f2b(jb.src[r * 15 + c]) : 0;
    }
}

// ================= centroid =================
__global__ __launch_bounds__(256) void k_centroid(const float* __restrict__ state,
                                                  float* __restrict__ cent) {
    int d = blockIdx.x;
    __shared__ float red[256];
    float s = 0.f;
    for (int r = threadIdx.x; r < RIG_; r += 256) s += state[r * 6 + d];
    red[threadIdx.x] = s; __syncthreads();
    for (int o = 128; o > 0; o >>= 1) {
        if (threadIdx.x < o) red[threadIdx.x] += red[threadIdx.x + o];
        __syncthreads();
    }
    if (threadIdx.x == 0) cent[d] = red[0] / (float)RIG_;
}

// ================= particle (col-split, persistent): feat(15) -> {P, Q, pe MLP, T} =====
__global__ __launch_bounds__(512, 4) void k_particle_ext(
        const float* __restrict__ state, const float* __restrict__ attr,
        const float* __restrict__ cent,
        const u16* __restrict__ w0r, const u16* __restrict__ w0s,   // [128][32]
        const u16* __restrict__ pew0, const float* __restrict__ pe_b0, // [128][32]
        const u16* __restrict__ pew1, const float* __restrict__ pe_b1, // [128][128]
        const u16* __restrict__ wp,                                    // [128][128]
        u16* __restrict__ P, u16* __restrict__ Q, u16* __restrict__ T) {
    __shared__ float in_s[64][16];
    __shared__ u16 INF[16 * 16 * 8];
    __shared__ __align__(16) u16 BUFA[64 * 128];
    __shared__ __align__(16) u16 BUFB[64 * 128];
    int t = threadIdx.x;
    int w = t >> 6, lane = t & 63, mm = lane & 15, quad = lane >> 4;
    int colw = w * 16 + mm;
    bf16x8 W0Rf = *(const bf16x8*)(w0r  + (size_t)colw * 32 + quad * 8);
    bf16x8 W0Sf = *(const bf16x8*)(w0s  + (size_t)colw * 32 + quad * 8);
    bf16x8 PE0f = *(const bf16x8*)(pew0 + (size_t)colw * 32 + quad * 8);
    bf16x8 PE1f[4], WPf[4];
    #pragma unroll
    for (int kc = 0; kc < 4; kc++) {
        PE1f[kc] = *(const bf16x8*)(pew1 + (size_t)colw * 128 + kc * 32 + quad * 8);
        WPf[kc]  = *(const bf16x8*)(wp   + (size_t)colw * 128 + kc * 32 + quad * 8);
    }
    float b0c = pe_b0[colw], b1c = pe_b1[colw];
    const int NTL = N_P / 64;
    for (int tile = blockIdx.x; tile < NTL; tile += gridDim.x) {
        int base = tile * 64;
        bar_l();                              // prev tile's INF/BUFB reads done
        // stage feat(15) -> in_s
        for (int it = t; it < 64 * 15; it += 512) {
            int r = it / 15, c = it % 15;
            int p = base + r;
            float v;
            if (c < 3)      v = attr[p * 3 + c];
            else if (c < 9) v = (p < RIG_) ? (state[p * 6 + (c - 3)] - cent[c - 3]) : 0.0f;
            else            v = state[p * 6 + (c - 9)];
            in_s[r][c] = v;
        }
        bar_l();                              // in_s visible
        // pack INF frags (first 256 threads cover 64x32)
        if (t < 256) {
            int wv = t >> 6, kq4 = (t >> 4) & 3, m = t & 15;
            int e = wv * 16 + m;
            u16 tmp[8];
            #pragma unroll
            for (int j = 0; j < 8; j++) {
                int k = kq4 * 8 + j;
                tmp[j] = (k < 15) ? f2b(in_s[e][k]) : (u16)0;
            }
            *(uint4*)&INF[FIDX(wv * 4 + kq4, m)] = *(uint4*)tmp;
        }
        bar_l();                              // INF visible
        bf16x8 af0[4];
        #pragma unroll
        for (int eg = 0; eg < 4; eg++)
            af0[eg] = *(const bf16x8*)&INF[FIDX(eg * 4 + quad, mm)];
        // P = W0r @ feat
        {
            f32x4 a[4] = {};
            #pragma unroll
            for (int eg = 0; eg < 4; eg++) a[eg] = MFMA(af0[eg], W0Rf, a[eg]);
            #pragma unroll
            for (int eg = 0; eg < 4; eg++)
                #pragma unroll
                for (int rg = 0; rg < 4; rg++)
                    P[(size_t)(base + eg * 16 + quad * 4 + rg) * 128 + colw] = f2b(a[eg][rg]);
        }
        // Q = W0s @ feat
        {
            f32x4 a[4] = {};
            #pragma unroll
            for (int eg = 0; eg < 4; eg++) a[eg] = MFMA(af0[eg], W0Sf, a[eg]);
            #pragma unroll
            for (int eg = 0; eg < 4; eg++)
                #pragma unroll
                for (int rg = 0; rg < 4; rg++)
                    Q[(size_t)(base + eg * 16 + quad * 4 + rg) * 128 + colw] = f2b(a[eg][rg]);
        }
        // pe L1 -> BUFA (frag)
        {
            f32x4 a[4] = {};
            #pragma unroll
            for (int eg = 0; eg < 4; eg++) a[eg] = MFMA(af0[eg], PE0f, a[eg]);
            #pragma unroll
            for (int eg = 0; eg < 4; eg++)
                #pragma unroll
                for (int rg = 0; rg < 4; rg++)
                    BUFA[FIDX(eg * 16 + (colw >> 3), quad * 4 + rg) + (colw & 7)] =
                        f2b(fmaxf(a[eg][rg] + b0c, 0.f));
        }
        bar_l();                              // BUFA visible
        // pe L2 -> BUFB (frag)
        {
            f32x4 a[4] = {};
            #pragma unroll
            for (int eg = 0; eg < 4; eg++)
                #pragma unroll
                for (int kc = 0; kc < 4; kc++) {
                    bf16x8 af = *(const bf16x8*)&BUFA[FIDX(eg * 16 + kc * 4 + quad, mm)];
                    a[eg] = MFMA(af, PE1f[kc], a[eg]);
                }
            #pragma unroll
            for (int eg = 0; eg < 4; eg++)
                #pragma unroll
                for (int rg = 0; rg < 4; rg++)
                    BUFB[FIDX(eg * 16 + (colw >> 3), quad * 4 + rg) + (colw & 7)] =
                        f2b(fmaxf(a[eg][rg] + b1c, 0.f));
        }
        bar_l();                              // BUFB visible, BUFA reads done
        // T = Wp @ particle_encode
        {
            f32x4 a[4] = {};
            #pragma unroll
            for (int eg = 0; eg < 4; eg++)
                #pragma unroll
                for (int kc = 0; kc < 4; kc++) {
                    bf16x8 af = *(const bf16x8*)&BUFB[FIDX(eg * 16 + kc * 4 + quad, mm)];
                    a[eg] = MFMA(af, WPf[kc], a[eg]);
                }
            #pragma unroll
            for (int eg = 0; eg < 4; eg++)
                #pragma unroll
                for (int rg = 0; rg < 4; rg++)
                    T[(size_t)(base + eg * 16 + quad * 4 + rg) * 128 + colw] = f2b(a[eg][rg]);
        }
    }
}

// ================= relation (col-split, reg weights, dbuf, light barriers) ========
// 12 frags / 64 VGPR / 2 blocks/CU is the feasible optimum (r6/r8 proved the
// allocator refuses more resident weight frags). DO NOT RAISE.
__global__ __launch_bounds__(512, 4) void k_rel(
        const u16* __restrict__ P, const u16* __restrict__ Q,
        const float* __restrict__ Ra, const int4* __restrict__ edges,
        const float* __restrict__ re_w0_raw, const float* __restrict__ b0,
        const u16* __restrict__ w1b, const float* __restrict__ b1,
        const u16* __restrict__ w2b, const float* __restrict__ b2,
        const u16* __restrict__ wreb, const float* __restrict__ rpb,
        u16* __restrict__ Z, float* __restrict__ agg) {
    __shared__ __align__(16) u16 BUFA[64 * 136];
    __shared__ __align__(16) u16 BUFB[64 * 136];
    __shared__ int rv_s[2][64];
    __shared__ float wRa_s[128], b0_s[128], rpb_s[128];
    int t = threadIdx.x;
    if (t < 128) {
        wRa_s[t] = re_w0_raw[t * 31 + 30];
        b0_s[t] = b0[t]; rpb_s[t] = rpb[t];
    }
    int w = t >> 6, lane = t & 63, mm = lane & 15, quad = lane >> 4;
    int colw = w * 16 + mm;                   // fixed output column of this lane
    bf16x8 W1f[4], W2f[4], WEf[4];
    #pragma unroll
    for (int kc = 0; kc < 4; kc++) {
        W1f[kc] = *(const bf16x8*)(w1b  + (size_t)colw * 128 + kc * 32 + quad * 8);
        W2f[kc] = *(const bf16x8*)(w2b  + (size_t)colw * 128 + kc * 32 + quad * 8);
        WEf[kc] = *(const bf16x8*)(wreb + (size_t)colw * 128 + kc * 32 + quad * 8);
    }
    float b1c = b1[colw], b2c = b2[colw];
    int es = t >> 3, cs2 = (t & 7) * 2;       // stage mapping: edge, chunk base
    int egs = es >> 4, ms = es & 15;
    int sseg = t >> 7, cseg = t & 127;        // segsum mapping
    int zrow = t >> 3, zc0 = (t & 7) * 16;    // coalesced Z-store mapping
    const long NT = N_E / 64;
    const long stride = gridDim.x;

    long tile = blockIdx.x;
    // prefetch first tile's gather data
    uint4 upC0, upC1, uqC0, uqC1; float raC; int rvC;
    {
        long nb = tile * 64;
        int4 e = edges[nb + es];
        rvC = edges[nb + (t & 63)].x;
        raC = Ra[e.z];
        upC0 = *(const uint4*)(P + (size_t)e.x * 128 + (size_t)cs2 * 8);
        upC1 = *(const uint4*)(P + (size_t)e.x * 128 + (size_t)(cs2 + 1) * 8);
        uqC0 = *(const uint4*)(Q + (size_t)e.y * 128 + (size_t)cs2 * 8);
        uqC1 = *(const uint4*)(Q + (size_t)e.y * 128 + (size_t)(cs2 + 1) * 8);
    }
    __syncthreads();                           // init: wRa_s/b0_s/rpb_s visible
    int p = 0;
    for (; tile < NT; tile += stride) {
        long base = tile * 64;
        long ntile = tile + stride;
        bool hn = ntile < NT;
        // next tile: index loads (latency covered by stage+layers)
        int4 eN = make_int4(0, 0, 0, 0); int rvN = 0;
        if (hn) {
            long nb = ntile * 64;
            eN  = edges[nb + es];
            rvN = edges[nb + (t & 63)].x;
        }
        if (t < 64) rv_s[p][t] = rvC;
        // stage H1 = relu(P[rv] + Q[sv] + Ra*wRa + b0) -> BUFA (frag layout)
        {
            #pragma unroll
            for (int ci = 0; ci < 2; ci++) {
                int kq = cs2 + ci;
                uint4 up = ci ? upC1 : upC0;
                uint4 uq = ci ? uqC1 : uqC0;
                const u16* pp = (const u16*)&up; const u16* qq = (const u16*)&uq;
                u16 outv[8];
                #pragma unroll
                for (int j = 0; j < 8; j++) {
                    int c = kq * 8 + j;
                    float v = b2f(pp[j]) + b2f(qq[j]) + raC * wRa_s[c] + b0_s[c];
                    outv[j] = f2b(fmaxf(v, 0.f));
                }
                *(uint4*)&BUFA[FIDX(egs * 16 + kq, ms)] = *(uint4*)outv;
            }
        }
        bar_l();                               // bar1: BUFA + rv_s visible
        // next tile: data loads, in flight across the 4 MFMA layers
        uint4 upN0{}, upN1{}, uqN0{}, uqN1{}; float raN = 0.f;
        if (hn) {
            raN  = Ra[eN.z];
            upN0 = *(const uint4*)(P + (size_t)eN.x * 128 + (size_t)cs2 * 8);
            upN1 = *(const uint4*)(P + (size_t)eN.x * 128 + (size_t)(cs2 + 1) * 8);
            uqN0 = *(const uint4*)(Q + (size_t)eN.y * 128 + (size_t)cs2 * 8);
            uqN1 = *(const uint4*)(Q + (size_t)eN.y * 128 + (size_t)(cs2 + 1) * 8);
        }
        // layer2: read A (frag), write B (frag)
        {
            f32x4 acc[4] = {};
            #pragma unroll
            for (int eg = 0; eg < 4; eg++)
                #pragma unroll
                for (int kc = 0; kc < 4; kc++) {
                    bf16x8 af = *(const bf16x8*)&BUFA[FIDX(eg * 16 + kc * 4 + quad, mm)];
                    acc[eg] = MFMA(af, W1f[kc], acc[eg]);
                }
            #pragma unroll
            for (int eg = 0; eg < 4; eg++)
                #pragma unroll
                for (int rg = 0; rg < 4; rg++)
                    BUFB[FIDX(eg * 16 + (colw >> 3), quad * 4 + rg) + (colw & 7)] =
                        f2b(fmaxf(acc[eg][rg] + b1c, 0.f));
        }
        bar_l();                               // bar2: B visible, A reads done
        // layer3: read B (frag), write A (frag)
        {
            f32x4 acc[4] = {};
            #pragma unroll
            for (int eg = 0; eg < 4; eg++)
                #pragma unroll
                for (int kc = 0; kc < 4; kc++) {
                    bf16x8 af = *(const bf16x8*)&BUFB[FIDX(eg * 16 + kc * 4 + quad, mm)];
                    acc[eg] = MFMA(af, W2f[kc], acc[eg]);
                }
            #pragma unroll
            for (int eg = 0; eg < 4; eg++)
                #pragma unroll
                for (int rg = 0; rg < 4; rg++)
                    BUFA[FIDX(eg * 16 + (colw >> 3), quad * 4 + rg) + (colw & 7)] =
                        f2b(fmaxf(acc[eg][rg] + b2c, 0.f));
        }
        bar_l();                               // bar3: A visible, B reads done
        // layer4: Z = Wre @ relenc (read A frag); raw bf16 Z -> BUFB (stride 136)
        {
            f32x4 zacc[4] = {};
            #pragma unroll
            for (int eg = 0; eg < 4; eg++)
                #pragma unroll
                for (int kc = 0; kc < 4; kc++) {
                    bf16x8 af = *(const bf16x8*)&BUFA[FIDX(eg * 16 + kc * 4 + quad, mm)];
                    zacc[eg] = MFMA(af, WEf[kc], zacc[eg]);
                }
            #pragma unroll
            for (int eg = 0; eg < 4; eg++)
                #pragma unroll
                for (int rg = 0; rg < 4; rg++)
                    BUFB[(eg * 16 + quad * 4 + rg) * 136 + colw] = f2b(zacc[eg][rg]);
        }
        bar_l();                               // bar4: raw-Z staging visible
        // coalesced Z store: 32 contiguous bytes per thread
        {
            uint4 z0 = *(const uint4*)&BUFB[zrow * 136 + zc0];
            uint4 z1 = *(const uint4*)&BUFB[zrow * 136 + zc0 + 8];
            *(uint4*)&Z[(base + zrow) * 128 + zc0]     = z0;
            *(uint4*)&Z[(base + zrow) * 128 + zc0 + 8] = z1;
        }
        // run-length segmented sum of relu(Z + rp_b); interior runs -> plain store
        {
            int r0 = sseg * 16;
            int cur = rv_s[p][r0];
            float a = fmaxf(b2f(BUFB[r0 * 136 + cseg]) + rpb_s[cseg], 0.f);
            bool first = true;
            for (int rr = r0 + 1; rr < r0 + 16; rr++) {
                int n = rv_s[p][rr];
                float v = fmaxf(b2f(BUFB[rr * 136 + cseg]) + rpb_s[cseg], 0.f);
                if (n == cur) a += v;
                else {
                    if (first) atomicAdd(&agg[(size_t)cur * 128 + cseg], a);
                    else       agg[(size_t)cur * 128 + cseg] = a;
                    first = false; cur = n; a = v;
                }
            }
            atomicAdd(&agg[(size_t)cur * 128 + cseg], a);
        }
        // rotate prefetched gather data
        if (hn) { upC0 = upN0; upC1 = upN1; uqC0 = uqN0; uqC1 = uqN1; raC = raN; rvC = rvN; }
        p ^= 1;
    }
}

// ================= node update step 1 (col-split, register-resident Wa/Wr/Ws) ======
__global__ __launch_bounds__(512, 4) void k_node2(
        const float* __restrict__ agg, const u16* __restrict__ T,
        const u16* __restrict__ wab, const float* __restrict__ ppb,
        const u16* __restrict__ wrb, const u16* __restrict__ wsb,
        u16* __restrict__ U, u16* __restrict__ V) {
    __shared__ __align__(16) u16 BUFA[64 * 128];
    __shared__ __align__(16) u16 BUFB[64 * 128];
    int t = threadIdx.x;
    int w = t >> 6, lane = t & 63, mm = lane & 15, quad = lane >> 4;
    int colw = w * 16 + mm;
    bf16x8 WAf[4], WRf[4], WSf[4];
    #pragma unroll
    for (int kc = 0; kc < 4; kc++) {
        WAf[kc] = *(const bf16x8*)(wab + (size_t)colw * 128 + kc * 32 + quad * 8);
        WRf[kc] = *(const bf16x8*)(wrb + (size_t)colw * 128 + kc * 32 + quad * 8);
        WSf[kc] = *(const bf16x8*)(wsb + (size_t)colw * 128 + kc * 32 + quad * 8);
    }
    float ppbc = ppb[colw];
    int es = t >> 3, cs2 = (t & 7) * 2;
    int egs = es >> 4, ms = es & 15;
    const int NTL = N_P / 64;
    for (int tile = blockIdx.x; tile < NTL; tile += gridDim.x) {
        long base = (long)tile * 64;
        __syncthreads();                       // prev tile's BUFB reads done
        // stage agg -> BUFA (frag layout)
        #pragma unroll
        for (int ci = 0; ci < 2; ci++) {
            int kq = cs2 + ci;
            const float* src = agg + (base + es) * 128 + kq * 8;
            float4 f0 = *(const float4*)src, f1 = *(const float4*)(src + 4);
            uint4 v;
            v.x = pk2(f0.x, f0.y); v.y = pk2(f0.z, f0.w);
            v.z = pk2(f1.x, f1.y); v.w = pk2(f1.z, f1.w);
            *(uint4*)&BUFA[FIDX(egs * 16 + kq, ms)] = v;
        }
        bar_l();                               // BUFA visible
        // eff = relu(Wa@agg + T + ppb) -> BUFB (frag layout)
        {
            f32x4 acc[4] = {};
            #pragma unroll
            for (int eg = 0; eg < 4; eg++)
                #pragma unroll
                for (int kc = 0; kc < 4; kc++) {
                    bf16x8 af = *(const bf16x8*)&BUFA[FIDX(eg * 16 + kc * 4 + quad, mm)];
                    acc[eg] = MFMA(af, WAf[kc], acc[eg]);
                }
            #pragma unroll
            for (int eg = 0; eg < 4; eg++)
                #pragma unroll
                for (int rg = 0; rg < 4; rg++) {
                    long row = base + eg * 16 + quad * 4 + rg;
                    float v = acc[eg][rg] + b2f(T[row * 128 + colw]) + ppbc;
                    BUFB[FIDX(eg * 16 + (colw >> 3), quad * 4 + rg) + (colw & 7)] =
                        f2b(fmaxf(v, 0.f));
                }
        }
        bar_l();                               // BUFB visible, BUFA reads done
        // U = Wr@eff, V = Ws@eff (single pass over BUFB)
        {
            f32x4 au[4] = {}, av[4] = {};
            #pragma unroll
            for (int eg = 0; eg < 4; eg++)
                #pragma unroll
                for (int kc = 0; kc < 4; kc++) {
                    bf16x8 af = *(const bf16x8*)&BUFB[FIDX(eg * 16 + kc * 4 + quad, mm)];
                    au[eg] = MFMA(af, WRf[kc], au[eg]);
                    av[eg] = MFMA(af, WSf[kc], av[eg]);
                }
            #pragma unroll
            for (int eg = 0; eg < 4; eg++)
                #pragma unroll
                for (int rg = 0; rg < 4; rg++) {
                    long row = base + eg * 16 + quad * 4 + rg;
                    U[row * 128 + colw] = f2b(au[eg][rg]);
                    V[row * 128 + colw] = f2b(av[eg][rg]);
                }
        }
    }
}

// ================= node update step 2 (col-split) + fused fluid MLP + rigid pool ====
__global__ __launch_bounds__(512, 4) void k_node2fl(
        const float* __restrict__ agg, const u16* __restrict__ T,
        const u16* __restrict__ wab, const float* __restrict__ ppb,
        float* __restrict__ pooledsum,
        const u16* __restrict__ w0b, const float* __restrict__ b0,
        const u16* __restrict__ w1b, const float* __restrict__ b1,
        const u16* __restrict__ w2b, const float* __restrict__ b2,
        float* __restrict__ out) {
    __shared__ __align__(16) u16 BUFA[64 * 128];
    __shared__ __align__(16) u16 BUFB[64 * 128];
    int t = threadIdx.x;
    int w = t >> 6, lane = t & 63, mm = lane & 15, quad = lane >> 4;
    int colw = w * 16 + mm;
    bf16x8 WAf[4], W0f[4], W1f[4];
    #pragma unroll
    for (int kc = 0; kc < 4; kc++) {
        WAf[kc] = *(const bf16x8*)(wab + (size_t)colw * 128 + kc * 32 + quad * 8);
        W0f[kc] = *(const bf16x8*)(w0b + (size_t)colw * 128 + kc * 32 + quad * 8);
        W1f[kc] = *(const bf16x8*)(w1b + (size_t)colw * 128 + kc * 32 + quad * 8);
    }
    float ppbc = ppb[colw], b0c = b0[colw], b1c = b1[colw];
    int es = t >> 3, cs2 = (t & 7) * 2;
    int egs = es >> 4, ms = es & 15;
    const int NTL = N_P / 64;
    for (int tile = blockIdx.x; tile < NTL; tile += gridDim.x) {
        long base = (long)tile * 64;
        bool fluid = base >= RIG_;
        bar_l();                               // prev tile's BUF reads done
        // stage agg -> BUFA (frag layout)
        #pragma unroll
        for (int ci = 0; ci < 2; ci++) {
            int kq = cs2 + ci;
            const float* src = agg + (base + es) * 128 + kq * 8;
            float4 f0 = *(const float4*)src, f1 = *(const float4*)(src + 4);
            uint4 v;
            v.x = pk2(f0.x, f0.y); v.y = pk2(f0.z, f0.w);
            v.z = pk2(f1.x, f1.y); v.w = pk2(f1.z, f1.w);
            *(uint4*)&BUFA[FIDX(egs * 16 + kq, ms)] = v;
        }
        bar_l();                               // BUFA visible
        // eff = relu(Wa@agg + T + ppb)
        f32x4 acc[4] = {};
        #pragma unroll
        for (int eg = 0; eg < 4; eg++)
            #pragma unroll
            for (int kc = 0; kc < 4; kc++) {
                bf16x8 af = *(const bf16x8*)&BUFA[FIDX(eg * 16 + kc * 4 + quad, mm)];
                acc[eg] = MFMA(af, WAf[kc], acc[eg]);
            }
        if (!fluid) {
            // rigid: per-lane col partial sum over its 16 rows, reduce across quads
            float s = 0.f;
            #pragma unroll
            for (int eg = 0; eg < 4; eg++)
                #pragma unroll
                for (int rg = 0; rg < 4; rg++) {
                    long row = base + eg * 16 + quad * 4 + rg;
                    float v = acc[eg][rg] + b2f(T[row * 128 + colw]) + ppbc;
                    s += b2f(f2b(fmaxf(v, 0.f)));
                }
            s += __shfl_xor(s, 16);
            s += __shfl_xor(s, 32);
            if (quad == 0) atomicAdd(&pooledsum[colw], s);
            continue;                          // block-uniform
        }
        #pragma unroll
        for (int eg = 0; eg < 4; eg++)
            #pragma unroll
            for (int rg = 0; rg < 4; rg++) {
                long row = base + eg * 16 + quad * 4 + rg;
                float v = acc[eg][rg] + b2f(T[row * 128 + colw]) + ppbc;
                BUFB[FIDX(eg * 16 + (colw >> 3), quad * 4 + rg) + (colw & 7)] =
                    f2b(fmaxf(v, 0.f));
            }
        bar_l();                               // BUFB visible, BUFA reads done
        // fluid L0: BUFB -> BUFA
        {
            f32x4 a[4] = {};
            #pragma unroll
            for (int eg = 0; eg < 4; eg++)
                #pragma unroll
                for (int kc = 0; kc < 4; kc++) {
                    bf16x8 af = *(const bf16x8*)&BUFB[FIDX(eg * 16 + kc * 4 + quad, mm)];
                    a[eg] = MFMA(af, W0f[kc], a[eg]);
                }
            #pragma unroll
            for (int eg = 0; eg < 4; eg++)
                #pragma unroll
                for (int rg = 0; rg < 4; rg++)
                    BUFA[FIDX(eg * 16 + (colw >> 3), quad * 4 + rg) + (colw & 7)] =
                        f2b(fmaxf(a[eg][rg] + b0c, 0.f));
        }
        bar_l();                               // BUFA visible, BUFB reads done
        // fluid L1: BUFA -> BUFB
        {
            f32x4 a[4] = {};
            #pragma unroll
            for (int eg = 0; eg < 4; eg++)
                #pragma unroll
                for (int kc = 0; kc < 4; kc++) {
                    bf16x8 af = *(const bf16x8*)&BUFA[FIDX(eg * 16 + kc * 4 + quad, mm)];
                    a[eg] = MFMA(af, W1f[kc], a[eg]);
                }
            #pragma unroll
            for (int eg = 0; eg < 4; eg++)
                #pragma unroll
                for (int rg = 0; rg < 4; rg++)
                    BUFB[FIDX(eg * 16 + (colw >> 3), quad * 4 + rg) + (colw & 7)] =
                        f2b(fmaxf(a[eg][rg] + b1c, 0.f));
        }
        bar_l();                               // BUFB visible
        // fluid L2 -> out: waves 0-3 handle row-tiles 0-3 (w2b streamed, 4KB)
        if (w < 4) {
            f32x4 a1 = {};
            #pragma unroll
            for (int kc = 0; kc < 4; kc++) {
                bf16x8 af = *(const bf16x8*)&BUFB[FIDX(w * 16 + kc * 4 + quad, mm)];
                bf16x8 bf = *(const bf16x8*)(w2b + (size_t)mm * 128 + kc * 32 + quad * 8);
                a1 = MFMA(af, bf, a1);
            }
            if (mm < 3) {
                float bv = b2[mm];
                #pragma unroll
                for (int rg = 0; rg < 4; rg++) {
                    long row = base + w * 16 + quad * 4 + rg;
                    out[row * 3 + mm] = a1[rg] + bv;
                }
            }
        }
    }
}

// ================= step-2 edge (persistent, pipelined): relu(Z+U[rv]+V[sv]+b) -> segsum ==
__global__ __launch_bounds__(512, 4) void k_edge2(
        const u16* __restrict__ Z, const u16* __restrict__ U, const u16* __restrict__ V,
        const int4* __restrict__ edges,
        const float* __restrict__ rpb, float* __restrict__ agg) {
    __shared__ __align__(16) u16 S16[2][64 * 136];
    __shared__ int rv_s[2][64];
    __shared__ float rpb_s[128];
    int t = threadIdx.x;
    if (t < 128) rpb_s[t] = rpb[t];
    int ec = t >> 3, cc = (t & 7) * 16;       // edge, col-chunk base
    int sseg = t >> 7, cseg = t & 127;        // segsum mapping (4 strips of 16)
    const long NT = N_E / 64;
    const long stride = gridDim.x;

    long tile = blockIdx.x;
    // prefetch first tile's rows
    uint4 zC0, zC1, uC0, uC1, vC0, vC1; int rvC;
    {
        long nb = tile * 64;
        int4 e = edges[nb + ec];
        rvC = edges[nb + (t & 63)].x;
        const u16* zp = Z + (nb + ec) * 128 + cc;
        zC0 = *(const uint4*)zp; zC1 = *(const uint4*)(zp + 8);
        const u16* up = U + (size_t)e.x * 128 + cc;
        uC0 = *(const uint4*)up; uC1 = *(const uint4*)(up + 8);
        const u16* vp = V + (size_t)e.y * 128 + cc;
        vC0 = *(const uint4*)vp; vC1 = *(const uint4*)(vp + 8);
    }
    __syncthreads();                           // rpb_s visible
    int p = 0;
    for (; tile < NT; tile += stride) {
        long ntile = tile + stride;
        bool hn = ntile < NT;
        if (t < 64) rv_s[p][t] = rvC;
        // stage relu(z + u + v + rpb) -> S16[p] from prefetched registers
        {
            const u16* zz = (const u16*)&zC0; const u16* uu = (const u16*)&uC0;
            const u16* vv = (const u16*)&vC0;
            u16 o[8];
            #pragma unroll
            for (int j = 0; j < 8; j++)
                o[j] = f2b(fmaxf(b2f(zz[j]) + b2f(uu[j]) + b2f(vv[j]) + rpb_s[cc + j], 0.f));
            *(uint4*)&S16[p][ec * 136 + cc] = *(uint4*)o;
            zz = (const u16*)&zC1; uu = (const u16*)&uC1; vv = (const u16*)&vC1;
            #pragma unroll
            for (int j = 0; j < 8; j++)
                o[j] = f2b(fmaxf(b2f(zz[j]) + b2f(uu[j]) + b2f(vv[j]) + rpb_s[cc + 8 + j], 0.f));
            *(uint4*)&S16[p][ec * 136 + cc + 8] = *(uint4*)o;
        }
        // next tile's loads: in flight across the barrier + segsum
        uint4 zN0{}, zN1{}, uN0{}, uN1{}, vN0{}, vN1{}; int rvN = 0;
        if (hn) {
            long nb = ntile * 64;
            int4 e = edges[nb + ec];
            rvN = edges[nb + (t & 63)].x;
            const u16* zp = Z + (nb + ec) * 128 + cc;
            zN0 = *(const uint4*)zp; zN1 = *(const uint4*)(zp + 8);
            const u16* up = U + (size_t)e.x * 128 + cc;
            uN0 = *(const uint4*)up; uN1 = *(const uint4*)(up + 8);
            const u16* vp = V + (size_t)e.y * 128 + cc;
            vN0 = *(const uint4*)vp; vN1 = *(const uint4*)(vp + 8);
        }
        bar_l();                               // S16[p] + rv_s[p] visible
        // run-length segmented sum; interior runs -> plain store
        {
            int r0 = sseg * 16;
            int cur = rv_s[p][r0];
            float a = b2f(S16[p][r0 * 136 + cseg]);
            bool first = true;
            for (int rr = r0 + 1; rr < r0 + 16; rr++) {
                int n = rv_s[p][rr];
                float v = b2f(S16[p][rr * 136 + cseg]);
                if (n == cur) a += v;
                else {
                    if (first) atomicAdd(&agg[(size_t)cur * 128 + cseg], a);
                    else       agg[(size_t)cur * 128 + cseg] = a;
                    first = false; cur = n; a = v;
                }
            }
            atomicAdd(&agg[(size_t)cur * 128 + cseg], a);
        }
        // rotate prefetched rows
        if (hn) { zC0 = zN0; zC1 = zN1; uC0 = uN0; uC1 = uN1; vC0 = vN0; vC1 = vN1; rvC = rvN; }
        p ^= 1;
    }
}

// ================= rigid head (pooled = sum/RIG) =================
__global__ __launch_bounds__(128) void k_rigid_head(
        const float* __restrict__ pooledsum,
        const float* __restrict__ w0, const float* __restrict__ b0,
        const float* __restrict__ w1, const float* __restrict__ b1,
        const float* __restrict__ w2, const float* __restrict__ b2,
        float* __restrict__ rig) {
    __shared__ float pl[128], ha[128], hb[128], tv[7];
    int t = threadIdx.x;
    pl[t] = pooledsum[t] * (1.0f / (float)RIG_);
    __syncthreads();
    float a = b0[t];
    for (int k = 0; k < 128; k++) a += w0[t * 128 + k] * pl[k];
    ha[t] = fmaxf(a, 0.f);
    __syncthreads();
    a = b1[t];
    for (int k = 0; k < 128; k++) a += w1[t * 128 + k] * ha[k];
    hb[t] = fmaxf(a, 0.f);
    __syncthreads();
    if (t < 7) {
        float s = b2[t];
        for (int k = 0; k < 128; k++) s += w2[t * 128 + k] * hb[k];
        tv[t] = s;
    }
    __syncthreads();
    if (t == 0) {
        float w = tv[0], x = tv[1], y = tv[2], z = tv[3];
        float n = sqrtf(w * w + x * x + y * y + z * z);
        w /= n; x /= n; y /= n; z /= n;
        rig[0] = 1.f - 2.f * (y * y + z * z); rig[1] = 2.f * (x * y + z * w); rig[2] = 2.f * (x * z - y * w);
        rig[3] = 2.f * (x * y - z * w); rig[4] = 1.f - 2.f * (x * x + z * z); rig[5] = 2.f * (y * z + x * w);
        rig[6] = 2.f * (x * z + y * w); rig[7] = 2.f * (y * z - x * w); rig[8] = 1.f - 2.f * (x * x + y * y);
        rig[9] = tv[4]; rig[10] = tv[5]; rig[11] = tv[6];
    }
}

// ================= rigid output =================
__global__ __launch_bounds__(256) void k_rigid_out(
        const float* __restrict__ state, const float* __restrict__ cent,
        const float* __restrict__ rig, float* __restrict__ out) {
    int i = blockIdx.x * 256 + threadIdx.x;
    if (i >= RIG_) return;
    float p0[3], d[3];
    #pragma unroll
    for (int k = 0; k < 3; k++) { p0[k] = state[i * 6 + k]; d[k] = p0[k] - cent[k]; }
    #pragma unroll
    for (int j = 0; j < 3; j++) {
        float p1 = rig[0 * 3 + j] * d[0] + rig[1 * 3 + j] * d[1] + rig[2 * 3 + j] * d[2]
                 + rig[9 + j] + cent[j];
        out[i * 3 + j] = (p1 - p0[j]) * 60.0f;
    }
}

// ================= host =================
extern "C" void kernel_launch(void* const* d_in, const int* in_sizes, int n_in,
                              void* d_out, int out_size, void* d_ws, size_t ws_size,
                              hipStream_t stream) {
    const float* state = (const float*)d_in[0];
    const float* attr  = (const float*)d_in[1];
    const float* Ra    = (const float*)d_in[2];
    const int*   recv  = (const int*)d_in[3];
    const int*   send  = (const int*)d_in[4];
    const float* pe_w0 = (const float*)d_in[5];  const float* pe_b0 = (const float*)d_in[6];
    const float* pe_w1 = (const float*)d_in[7];  const float* pe_b1 = (const float*)d_in[8];
    const float* re_w0 = (const float*)d_in[9];  const float* re_b0 = (const float*)d_in[10];
    const float* re_w1 = (const float*)d_in[11]; const float* re_b1 = (const float*)d_in[12];
    const float* re_w2 = (const float*)d_in[13]; const float* re_b2 = (const float*)d_in[14];
    const float* rp_w  = (const float*)d_in[15]; const float* rp_b  = (const float*)d_in[16];
    const float* pp_w  = (const float*)d_in[17]; const float* pp_b  = (const float*)d_in[18];
    const float* rg_w0 = (const float*)d_in[19]; const float* rg_b0 = (const float*)d_in[20];
    const float* rg_w1 = (const float*)d_in[21]; const float* rg_b1 = (const float*)d_in[22];
    const float* rg_w2 = (const float*)d_in[23]; const float* rg_b2 = (const float*)d_in[24];
    const float* fl_w0 = (const float*)d_in[25]; const float* fl_b0 = (const float*)d_in[26];
    const float* fl_w1 = (const float*)d_in[27]; const float* fl_b1 = (const float*)d_in[28];
    const float* fl_w2 = (const float*)d_in[29]; const float* fl_b2 = (const float*)d_in[30];
    float* out = (float*)d_out;

    // ---- workspace carve-out ----
    char* p = (char*)d_ws;
    auto alloc = [&](size_t bytes) { char* r = p; p += (bytes + 255) / 256 * 256; return r; };
    float* cent    = (float*)alloc(8 * 4);
    float* pooled  = (float*)alloc(128 * 4);
    float* rig     = (float*)alloc(16 * 4);
    u32*   rowhead = (u32*)alloc((size_t)N_P * 4);
    u32*   bsum    = (u32*)alloc(256 * 4);
    int4*  edges   = (int4*)alloc((size_t)N_E * 16);
    float* agg     = (float*)alloc((size_t)N_P * 128 * 4);
    u16*   Z       = (u16*)alloc((size_t)N_E * 128 * 2);
    u16*   T       = (u16*)alloc((size_t)N_P * 128 * 2);
    u16*   P       = (u16*)alloc((size_t)N_P * 128 * 2);   // aliased as U after k_rel
    u16*   Q       = (u16*)alloc((size_t)N_P * 128 * 2);   // aliased as V after k_rel
    u16*   wreb    = (u16*)alloc(128 * 128 * 2);
    u16*   wrb     = (u16*)alloc(128 * 128 * 2);
    u16*   wsb     = (u16*)alloc(128 * 128 * 2);
    u16*   wpb     = (u16*)alloc(128 * 128 * 2);
    u16*   wab     = (u16*)alloc(128 * 128 * 2);
    u16*   rw1b    = (u16*)alloc(128 * 128 * 2);
    u16*   rw2b    = (u16*)alloc(128 * 128 * 2);
    u16*   pew1b   = (u16*)alloc(128 * 128 * 2);
    u16*   flw0b   = (u16*)alloc(128 * 128 * 2);
    u16*   flw1b   = (u16*)alloc(128 * 128 * 2);
    u16*   flw2b   = (u16*)alloc(16 * 128 * 2);
    u16*   w0rb    = (u16*)alloc(128 * 32 * 2);
    u16*   w0sb    = (u16*)alloc(128 * 32 * 2);
    u16*   pew0b   = (u16*)alloc(128 * 32 * 2);
    size_t need = (size_t)(p - (char*)d_ws);
    if (ws_size < need) {
        fprintf(stderr, "kernel_launch: ws_size %zu < needed %zu\n", ws_size, need);
        return;
    }
    u16* U = P; u16* V = Q;

    // ---- sort edges by recv ----
    hipMemsetAsync(rowhead, 0, (size_t)N_P * 4, stream);
    k_hist<<<N_E / 256, 256, 0, stream>>>(recv, rowhead);
    k_scan1<<<N_P / 256, 256, 0, stream>>>(rowhead, bsum);
    k_scan2<<<1, 256, 0, stream>>>(bsum);
    k_scan3<<<N_P / 256, 256, 0, stream>>>(rowhead, bsum);
    k_scatter<<<N_E / 256, 256, 0, stream>>>(recv, send, rowhead, edges);

    // ---- weight conversion ----
    CvtArgs ca;
    int bs = 0;
    auto addjob = [&](int idx, const float* s, u16* d, int n, int mode) {
        ca.j[idx] = {s, d, n, mode, bs};
        bs += (n + 255) / 256;
    };
    addjob(0,  rp_w,        wreb,  128 * 128, 3);
    addjob(1,  rp_w + 128,  wrb,   128 * 128, 3);
    addjob(2,  rp_w + 256,  wsb,   128 * 128, 3);
    addjob(3,  pp_w,        wpb,   128 * 128, 4);
    addjob(4,  pp_w + 128,  wab,   128 * 128, 4);
    addjob(5,  re_w1,       rw1b,  128 * 128, 0);
    addjob(6,  re_w2,       rw2b,  128 * 128, 0);
    addjob(7,  pe_w1,       pew1b, 128 * 128, 0);
    addjob(8,  fl_w0,       flw0b, 128 * 128, 0);
    addjob(9,  fl_w1,       flw1b, 128 * 128, 0);
    addjob(10, fl_w2,       flw2b, 16 * 128,  2);
    addjob(11, re_w0,       w0rb,  128 * 32,  5);
    addjob(12, re_w0,       w0sb,  128 * 32,  6);
    addjob(13, pe_w0,       pew0b, 128 * 32,  7);
    k_cvt_all<<<bs, 256, 0, stream>>>(ca);

    // ---- encoders ----
    k_centroid<<<6, 256, 0, stream>>>(state, cent);
    k_particle_ext<<<512, 512, 0, stream>>>(state, attr, cent,
                                            w0rb, w0sb, pew0b, pe_b0,
                                            pew1b, pe_b1, wpb, P, Q, T);

    // ---- step 1: rel-enc + Z + fused agg ----
    hipMemsetAsync(agg, 0, (size_t)N_P * 128 * 4, stream);
    k_rel<<<512, 512, 0, stream>>>(P, Q, Ra, edges,
                                   re_w0, re_b0, rw1b, re_b1, rw2b, re_b2,
                                   wreb, rp_b, Z, agg);
    // node update fused with U/V production (col-split, persistent)
    k_node2<<<512, 512, 0, stream>>>(agg, T, wab, pp_b, wrb, wsb, U, V);

    // ---- step 2 ----
    hipMemsetAsync(agg, 0, (size_t)N_P * 128 * 4, stream);
    hipMemsetAsync(pooled, 0, 128 * 4, stream);
    k_edge2<<<512, 512, 0, stream>>>(Z, U, V, edges, rp_b, agg);
    // node update fused with fluid MLP + rigid pooled accumulation (col-split)
    k_node2fl<<<512, 512, 0, stream>>>(agg, T, wab, pp_b, pooled,
                                       flw0b, fl_b0, flw1b, fl_b1,
                                       flw2b, fl_b2, out);

    // ---- heads (rigid) ----
    k_rigid_head<<<1, 128, 0, stream>>>(pooled, rg_w0, rg_b0, rg_w1, rg_b1, rg_w2, rg_b2, rig);
    k_rigid_out<<<(RIG_ + 255) / 256, 256, 0, stream>>>(state, cent, rig, out);
}

// Round 13
// 463.954 us; speedup vs baseline: 1.0053x; 1.0053x over previous
//
#include <hip/hip_runtime.h>
#include <hip/hip_bf16.h>
#include <cstdio>

#define N_P   65536
#define N_E   524288
#define RIG_  4096

typedef __attribute__((ext_vector_type(8))) short bf16x8;
typedef __attribute__((ext_vector_type(4))) float f32x4;
typedef unsigned short u16;
typedef unsigned int   u32;

__device__ __forceinline__ u16 f2b(float x) {
    __hip_bfloat16 h = __float2bfloat16(x);
    return *(u16*)&h;
}
__device__ __forceinline__ float b2f(u16 u) {
    union { unsigned u; float f; } c; c.u = ((unsigned)u) << 16; return c.f;
}
__device__ __forceinline__ unsigned pk2(float x, float y) {
    return (unsigned)f2b(x) | ((unsigned)f2b(y) << 16);
}
#define MFMA(a,b,c) __builtin_amdgcn_mfma_f32_16x16x32_bf16((a),(b),(c),0,0,0)

// NOTE r12 lesson: XOR bank-swizzle on the frag tiles cut SQ_LDS_BANK_CONFLICT
// 4x but REGRESSED total (+1%): conflicts were TLP-hidden, the extra address
// VALU was not. Linear frag layout restored. DO NOT RE-SWIZZLE.

// LDS-only barrier: waits LDS ops, does NOT drain global stores/atomics.
__device__ __forceinline__ void bar_l() {
    asm volatile("s_waitcnt lgkmcnt(0)\n\ts_barrier" ::: "memory");
}

// ================= sort: histogram / scan / scatter =================
__global__ __launch_bounds__(256) void k_hist(const int* __restrict__ recv,
                                              u32* __restrict__ cnt) {
    int i = blockIdx.x * 256 + threadIdx.x;
    if (i < N_E) atomicAdd(&cnt[recv[i]], 1u);
}
__global__ __launch_bounds__(256) void k_scan1(u32* __restrict__ data,
                                               u32* __restrict__ bsum) {
    __shared__ u32 s[256];
    int t = threadIdx.x, g = blockIdx.x * 256 + t;
    u32 v = data[g];
    s[t] = v; __syncthreads();
    for (int o = 1; o < 256; o <<= 1) {
        u32 x = (t >= o) ? s[t - o] : 0u;
        __syncthreads(); s[t] += x; __syncthreads();
    }
    data[g] = s[t] - v;
    if (t == 255) bsum[blockIdx.x] = s[255];
}
__global__ __launch_bounds__(256) void k_scan2(u32* __restrict__ bsum) {
    __shared__ u32 s[256];
    int t = threadIdx.x;
    u32 v = bsum[t];
    s[t] = v; __syncthreads();
    for (int o = 1; o < 256; o <<= 1) {
        u32 x = (t >= o) ? s[t - o] : 0u;
        __syncthreads(); s[t] += x; __syncthreads();
    }
    bsum[t] = s[t] - v;
}
__global__ __launch_bounds__(256) void k_scan3(u32* __restrict__ data,
                                               const u32* __restrict__ bsum) {
    int g = blockIdx.x * 256 + threadIdx.x;
    data[g] += bsum[blockIdx.x];
}
// packed edge record: {recv, send, Ra_bits, pad} -> one 16B store per edge.
// Ra folded in at scatter time kills the dependent Ra[perm] gather in k_rel
// (two-level load chain -> one load; Ra read here is fully coalesced).
__global__ __launch_bounds__(256) void k_scatter(const int* __restrict__ recv,
                                                 const int* __restrict__ send,
                                                 const float* __restrict__ Ra,
                                                 u32* __restrict__ head,
                                                 int4* __restrict__ edges) {
    int i = blockIdx.x * 256 + threadIdx.x;
    if (i < N_E) {
        int n = recv[i];
        u32 pos = atomicAdd(&head[n], 1u);
        edges[pos] = make_int4(n, send[i], __float_as_int(Ra[i]), 0);
    }
}

// ================= fused weight conversion =================
// modes: 0 plain; 2 pad-rows [3][128]->[16][128]; 3 col-slice stride 384;
// 4 col-slice stride 256; 5 W0r-select; 6 W0s-select; 7 pad15->32
struct CvtJob { const float* src; u16* dst; int n; int mode; int bstart; };
struct CvtArgs { CvtJob j[14]; };

__global__ __launch_bounds__(256) void k_cvt_all(CvtArgs a) {
    int b = blockIdx.x;
    int ji = 0;
    #pragma unroll
    for (int k = 1; k < 14; k++) if (b >= a.j[k].bstart) ji = k;
    CvtJob jb = a.j[ji];
    int i = (b - jb.bstart) * 256 + threadIdx.x;
    if (i >= jb.n) return;
    if (jb.mode == 0) {
        jb.dst[i] = f2b(jb.src[i]);
    } else if (jb.mode == 2) {
        int r = i >> 7;
        jb.dst[i] = (r < 3) ? f2b(jb.src[i]) : 0;
    } else if (jb.mode == 3) {
        int r = i >> 7, c = i & 127;
        jb.dst[i] = f2b(jb.src[r * 384 + c]);
    } else if (jb.mode == 4) {
        int r = i >> 7, c = i & 127;
        jb.dst[i] = f2b(jb.src[r * 256 + c]);
    } else if (jb.mode == 5) {               // W0r: [attr2_r(9), state_r(6)] cols
        int r = i >> 5, c = i & 31;
        float v = 0.f;
        if (c < 9)       v = jb.src[r * 31 + c];
        else if (c < 15) v = jb.src[r * 31 + 18 + (c - 9)];
        jb.dst[i] = f2b(v);
    } else if (jb.mode == 6) {               // W0s: [attr2_s(9), state_s(6)] cols
        int r = i >> 5, c = i & 31;
        float v = 0.f;
        if (c < 9)       v = jb.src[r * 31 + 9 + c];
        else if (c < 15) v = jb.src[r * 31 + 24 + (c - 9)];
        jb.dst[i] = f2b(v);
    } else {                                  // mode 7: [128][15] -> [128][32]
        int r = i >> 5, c = i & 31;
        jb.dst[i] = (c < 15) ? f2b(jb.src[r * 15 + c]) : 0;
    }
}

// ================= centroid =================
__global__ __launch_bounds__(256) void k_centroid(const float* __restrict__ state,
                                                  float* __restrict__ cent) {
    int d = blockIdx.x;
    __shared__ float red[256];
    float s = 0.f;
    for (int r = threadIdx.x; r < RIG_; r += 256) s += state[r * 6 + d];
    red[threadIdx.x] = s; __syncthreads();
    for (int o = 128; o > 0; o >>= 1) {
        if (threadIdx.x < o) red[threadIdx.x] += red[threadIdx.x + o];
        __syncthreads();
    }
    if (threadIdx.x == 0) cent[d] = red[0] / (float)RIG_;
}

// ================= particle (col-split, persistent): feat(15) -> {P, Q, pe MLP, T} =====
__global__ __launch_bounds__(512, 4) void k_particle_ext(
        const float* __restrict__ state, const float* __restrict__ attr,
        const float* __restrict__ cent,
        const u16* __restrict__ w0r, const u16* __restrict__ w0s,   // [128][32]
        const u16* __restrict__ pew0, const float* __restrict__ pe_b0, // [128][32]
        const u16* __restrict__ pew1, const float* __restrict__ pe_b1, // [128][128]
        const u16* __restrict__ wp,                                    // [128][128]
        u16* __restrict__ P, u16* __restrict__ Q, u16* __restrict__ T) {
    __shared__ float in_s[64][16];
    __shared__ u16 INF[64 * 32];
    __shared__ __align__(16) u16 BUFA[64 * 128];
    __shared__ __align__(16) u16 BUFB[64 * 128];
    int t = threadIdx.x;
    int w = t >> 6, lane = t & 63, mm = lane & 15, quad = lane >> 4;
    int colw = w * 16 + mm;
    bf16x8 W0Rf = *(const bf16x8*)(w0r  + (size_t)colw * 32 + quad * 8);
    bf16x8 W0Sf = *(const bf16x8*)(w0s  + (size_t)colw * 32 + quad * 8);
    bf16x8 PE0f = *(const bf16x8*)(pew0 + (size_t)colw * 32 + quad * 8);
    bf16x8 PE1f[4], WPf[4];
    #pragma unroll
    for (int kc = 0; kc < 4; kc++) {
        PE1f[kc] = *(const bf16x8*)(pew1 + (size_t)colw * 128 + kc * 32 + quad * 8);
        WPf[kc]  = *(const bf16x8*)(wp   + (size_t)colw * 128 + kc * 32 + quad * 8);
    }
    float b0c = pe_b0[colw], b1c = pe_b1[colw];
    const int NTL = N_P / 64;
    for (int tile = blockIdx.x; tile < NTL; tile += gridDim.x) {
        int base = tile * 64;
        bar_l();                              // prev tile's INF/BUFB reads done
        // stage feat(15) -> in_s
        for (int it = t; it < 64 * 15; it += 512) {
            int r = it / 15, c = it % 15;
            int p = base + r;
            float v;
            if (c < 3)      v = attr[p * 3 + c];
            else if (c < 9) v = (p < RIG_) ? (state[p * 6 + (c - 3)] - cent[c - 3]) : 0.0f;
            else            v = state[p * 6 + (c - 9)];
            in_s[r][c] = v;
        }
        bar_l();                              // in_s visible
        // pack INF frags (first 256 threads cover 64x32)
        if (t < 256) {
            int wv = t >> 6, kq4 = (t >> 4) & 3, m = t & 15;
            int e = wv * 16 + m;
            u16 tmp[8];
            #pragma unroll
            for (int j = 0; j < 8; j++) {
                int k = kq4 * 8 + j;
                tmp[j] = (k < 15) ? f2b(in_s[e][k]) : (u16)0;
            }
            *(uint4*)&INF[((wv * 4 + kq4) * 16 + m) * 8] = *(uint4*)tmp;
        }
        bar_l();                              // INF visible
        bf16x8 af0[4];
        #pragma unroll
        for (int eg = 0; eg < 4; eg++)
            af0[eg] = *(const bf16x8*)&INF[((eg * 4 + quad) * 16 + mm) * 8];
        // P = W0r @ feat
        {
            f32x4 a[4] = {};
            #pragma unroll
            for (int eg = 0; eg < 4; eg++) a[eg] = MFMA(af0[eg], W0Rf, a[eg]);
            #pragma unroll
            for (int eg = 0; eg < 4; eg++)
                #pragma unroll
                for (int rg = 0; rg < 4; rg++)
                    P[(size_t)(base + eg * 16 + quad * 4 + rg) * 128 + colw] = f2b(a[eg][rg]);
        }
        // Q = W0s @ feat
        {
            f32x4 a[4] = {};
            #pragma unroll
            for (int eg = 0; eg < 4; eg++) a[eg] = MFMA(af0[eg], W0Sf, a[eg]);
            #pragma unroll
            for (int eg = 0; eg < 4; eg++)
                #pragma unroll
                for (int rg = 0; rg < 4; rg++)
                    Q[(size_t)(base + eg * 16 + quad * 4 + rg) * 128 + colw] = f2b(a[eg][rg]);
        }
        // pe L1 -> BUFA (frag)
        {
            f32x4 a[4] = {};
            #pragma unroll
            for (int eg = 0; eg < 4; eg++) a[eg] = MFMA(af0[eg], PE0f, a[eg]);
            #pragma unroll
            for (int eg = 0; eg < 4; eg++)
                #pragma unroll
                for (int rg = 0; rg < 4; rg++)
                    BUFA[((eg * 16 + (colw >> 3)) * 16 + quad * 4 + rg) * 8 + (colw & 7)] =
                        f2b(fmaxf(a[eg][rg] + b0c, 0.f));
        }
        bar_l();                              // BUFA visible
        // pe L2 -> BUFB (frag)
        {
            f32x4 a[4] = {};
            #pragma unroll
            for (int eg = 0; eg < 4; eg++)
                #pragma unroll
                for (int kc = 0; kc < 4; kc++) {
                    bf16x8 af = *(const bf16x8*)&BUFA[((eg * 16 + kc * 4 + quad) * 16 + mm) * 8];
                    a[eg] = MFMA(af, PE1f[kc], a[eg]);
                }
            #pragma unroll
            for (int eg = 0; eg < 4; eg++)
                #pragma unroll
                for (int rg = 0; rg < 4; rg++)
                    BUFB[((eg * 16 + (colw >> 3)) * 16 + quad * 4 + rg) * 8 + (colw & 7)] =
                        f2b(fmaxf(a[eg][rg] + b1c, 0.f));
        }
        bar_l();                              // BUFB visible, BUFA reads done
        // T = Wp @ particle_encode
        {
            f32x4 a[4] = {};
            #pragma unroll
            for (int eg = 0; eg < 4; eg++)
                #pragma unroll
                for (int kc = 0; kc < 4; kc++) {
                    bf16x8 af = *(const bf16x8*)&BUFB[((eg * 16 + kc * 4 + quad) * 16 + mm) * 8];
                    a[eg] = MFMA(af, WPf[kc], a[eg]);
                }
            #pragma unroll
            for (int eg = 0; eg < 4; eg++)
                #pragma unroll
                for (int rg = 0; rg < 4; rg++)
                    T[(size_t)(base + eg * 16 + quad * 4 + rg) * 128 + colw] = f2b(a[eg][rg]);
        }
    }
}

// ================= relation (col-split, reg weights, dbuf, light barriers) ========
// 12 frags / 64 VGPR / 2 blocks/CU is the feasible optimum (r6/r8 proved the
// allocator refuses more resident weight frags). DO NOT RAISE.
__global__ __launch_bounds__(512, 4) void k_rel(
        const u16* __restrict__ P, const u16* __restrict__ Q,
        const int4* __restrict__ edges,
        const float* __restrict__ re_w0_raw, const float* __restrict__ b0,
        const u16* __restrict__ w1b, const float* __restrict__ b1,
        const u16* __restrict__ w2b, const float* __restrict__ b2,
        const u16* __restrict__ wreb, const float* __restrict__ rpb,
        u16* __restrict__ Z, float* __restrict__ agg) {
    __shared__ __align__(16) u16 BUFA[64 * 136];
    __shared__ __align__(16) u16 BUFB[64 * 136];
    __shared__ int rv_s[2][64];
    __shared__ float wRa_s[128], b0_s[128], rpb_s[128];
    int t = threadIdx.x;
    if (t < 128) {
        wRa_s[t] = re_w0_raw[t * 31 + 30];
        b0_s[t] = b0[t]; rpb_s[t] = rpb[t];
    }
    int w = t >> 6, lane = t & 63, mm = lane & 15, quad = lane >> 4;
    int colw = w * 16 + mm;                   // fixed output column of this lane
    bf16x8 W1f[4], W2f[4], WEf[4];
    #pragma unroll
    for (int kc = 0; kc < 4; kc++) {
        W1f[kc] = *(const bf16x8*)(w1b  + (size_t)colw * 128 + kc * 32 + quad * 8);
        W2f[kc] = *(const bf16x8*)(w2b  + (size_t)colw * 128 + kc * 32 + quad * 8);
        WEf[kc] = *(const bf16x8*)(wreb + (size_t)colw * 128 + kc * 32 + quad * 8);
    }
    float b1c = b1[colw], b2c = b2[colw];
    int es = t >> 3, cs2 = (t & 7) * 2;       // stage mapping: edge, chunk base
    int egs = es >> 4, ms = es & 15;
    int sseg = t >> 7, cseg = t & 127;        // segsum mapping
    int zrow = t >> 3, zc0 = (t & 7) * 16;    // coalesced Z-store mapping
    const long NT = N_E / 64;
    const long stride = gridDim.x;

    long tile = blockIdx.x;
    // prefetch first tile's gather data (Ra bits ride in edges.z: no 2nd-level gather)
    uint4 upC0, upC1, uqC0, uqC1; float raC; int rvC;
    {
        long nb = tile * 64;
        int4 e = edges[nb + es];
        rvC = edges[nb + (t & 63)].x;
        raC = __int_as_float(e.z);
        upC0 = *(const uint4*)(P + (size_t)e.x * 128 + (size_t)cs2 * 8);
        upC1 = *(const uint4*)(P + (size_t)e.x * 128 + (size_t)(cs2 + 1) * 8);
        uqC0 = *(const uint4*)(Q + (size_t)e.y * 128 + (size_t)cs2 * 8);
        uqC1 = *(const uint4*)(Q + (size_t)e.y * 128 + (size_t)(cs2 + 1) * 8);
    }
    __syncthreads();                           // init: wRa_s/b0_s/rpb_s visible
    int p = 0;
    for (; tile < NT; tile += stride) {
        long base = tile * 64;
        long ntile = tile + stride;
        bool hn = ntile < NT;
        // next tile: index loads (latency covered by stage+layers)
        int4 eN = make_int4(0, 0, 0, 0); int rvN = 0;
        if (hn) {
            long nb = ntile * 64;
            eN  = edges[nb + es];
            rvN = edges[nb + (t & 63)].x;
        }
        if (t < 64) rv_s[p][t] = rvC;
        // stage H1 = relu(P[rv] + Q[sv] + Ra*wRa + b0) -> BUFA (frag layout)
        {
            #pragma unroll
            for (int ci = 0; ci < 2; ci++) {
                int kq = cs2 + ci;
                uint4 up = ci ? upC1 : upC0;
                uint4 uq = ci ? uqC1 : uqC0;
                const u16* pp = (const u16*)&up; const u16* qq = (const u16*)&uq;
                u16 outv[8];
                #pragma unroll
                for (int j = 0; j < 8; j++) {
                    int c = kq * 8 + j;
                    float v = b2f(pp[j]) + b2f(qq[j]) + raC * wRa_s[c] + b0_s[c];
                    outv[j] = f2b(fmaxf(v, 0.f));
                }
                *(uint4*)&BUFA[((egs * 16 + kq) * 16 + ms) * 8] = *(uint4*)outv;
            }
        }
        bar_l();                               // bar1: BUFA + rv_s visible
        // next tile: data loads, in flight across the 4 MFMA layers
        uint4 upN0{}, upN1{}, uqN0{}, uqN1{}; float raN = 0.f;
        if (hn) {
            raN  = __int_as_float(eN.z);
            upN0 = *(const uint4*)(P + (size_t)eN.x * 128 + (size_t)cs2 * 8);
            upN1 = *(const uint4*)(P + (size_t)eN.x * 128 + (size_t)(cs2 + 1) * 8);
            uqN0 = *(const uint4*)(Q + (size_t)eN.y * 128 + (size_t)cs2 * 8);
            uqN1 = *(const uint4*)(Q + (size_t)eN.y * 128 + (size_t)(cs2 + 1) * 8);
        }
        // layer2: read A (frag), write B (frag)
        {
            f32x4 acc[4] = {};
            #pragma unroll
            for (int eg = 0; eg < 4; eg++)
                #pragma unroll
                for (int kc = 0; kc < 4; kc++) {
                    bf16x8 af = *(const bf16x8*)&BUFA[((eg * 16 + kc * 4 + quad) * 16 + mm) * 8];
                    acc[eg] = MFMA(af, W1f[kc], acc[eg]);
                }
            #pragma unroll
            for (int eg = 0; eg < 4; eg++)
                #pragma unroll
                for (int rg = 0; rg < 4; rg++)
                    BUFB[((eg * 16 + (colw >> 3)) * 16 + quad * 4 + rg) * 8 + (colw & 7)] =
                        f2b(fmaxf(acc[eg][rg] + b1c, 0.f));
        }
        bar_l();                               // bar2: B visible, A reads done
        // layer3: read B (frag), write A (frag)
        {
            f32x4 acc[4] = {};
            #pragma unroll
            for (int eg = 0; eg < 4; eg++)
                #pragma unroll
                for (int kc = 0; kc < 4; kc++) {
                    bf16x8 af = *(const bf16x8*)&BUFB[((eg * 16 + kc * 4 + quad) * 16 + mm) * 8];
                    acc[eg] = MFMA(af, W2f[kc], acc[eg]);
                }
            #pragma unroll
            for (int eg = 0; eg < 4; eg++)
                #pragma unroll
                for (int rg = 0; rg < 4; rg++)
                    BUFA[((eg * 16 + (colw >> 3)) * 16 + quad * 4 + rg) * 8 + (colw & 7)] =
                        f2b(fmaxf(acc[eg][rg] + b2c, 0.f));
        }
        bar_l();                               // bar3: A visible, B reads done
        // layer4: Z = Wre @ relenc (read A frag); raw bf16 Z -> BUFB (stride 136)
        {
            f32x4 zacc[4] = {};
            #pragma unroll
            for (int eg = 0; eg < 4; eg++)
                #pragma unroll
                for (int kc = 0; kc < 4; kc++) {
                    bf16x8 af = *(const bf16x8*)&BUFA[((eg * 16 + kc * 4 + quad) * 16 + mm) * 8];
                    zacc[eg] = MFMA(af, WEf[kc], zacc[eg]);
                }
            #pragma unroll
            for (int eg = 0; eg < 4; eg++)
                #pragma unroll
                for (int rg = 0; rg < 4; rg++)
                    BUFB[(eg * 16 + quad * 4 + rg) * 136 + colw] = f2b(zacc[eg][rg]);
        }
        bar_l();                               // bar4: raw-Z staging visible
        // coalesced Z store: 32 contiguous bytes per thread
        {
            uint4 z0 = *(const uint4*)&BUFB[zrow * 136 + zc0];
            uint4 z1 = *(const uint4*)&BUFB[zrow * 136 + zc0 + 8];
            *(uint4*)&Z[(base + zrow) * 128 + zc0]     = z0;
            *(uint4*)&Z[(base + zrow) * 128 + zc0 + 8] = z1;
        }
        // run-length segmented sum of relu(Z + rp_b); interior runs -> plain store
        {
            int r0 = sseg * 16;
            int cur = rv_s[p][r0];
            float a = fmaxf(b2f(BUFB[r0 * 136 + cseg]) + rpb_s[cseg], 0.f);
            bool first = true;
            for (int rr = r0 + 1; rr < r0 + 16; rr++) {
                int n = rv_s[p][rr];
                float v = fmaxf(b2f(BUFB[rr * 136 + cseg]) + rpb_s[cseg], 0.f);
                if (n == cur) a += v;
                else {
                    if (first) atomicAdd(&agg[(size_t)cur * 128 + cseg], a);
                    else       agg[(size_t)cur * 128 + cseg] = a;
                    first = false; cur = n; a = v;
                }
            }
            atomicAdd(&agg[(size_t)cur * 128 + cseg], a);
        }
        // rotate prefetched gather data
        if (hn) { upC0 = upN0; upC1 = upN1; uqC0 = uqN0; uqC1 = uqN1; raC = raN; rvC = rvN; }
        p ^= 1;
    }
}

// ================= node update step 1 (col-split, register-resident Wa/Wr/Ws) ======
__global__ __launch_bounds__(512, 4) void k_node2(
        const float* __restrict__ agg, const u16* __restrict__ T,
        const u16* __restrict__ wab, const float* __restrict__ ppb,
        const u16* __restrict__ wrb, const u16* __restrict__ wsb,
        u16* __restrict__ U, u16* __restrict__ V) {
    __shared__ __align__(16) u16 BUFA[64 * 128];
    __shared__ __align__(16) u16 BUFB[64 * 128];
    int t = threadIdx.x;
    int w = t >> 6, lane = t & 63, mm = lane & 15, quad = lane >> 4;
    int colw = w * 16 + mm;
    bf16x8 WAf[4], WRf[4], WSf[4];
    #pragma unroll
    for (int kc = 0; kc < 4; kc++) {
        WAf[kc] = *(const bf16x8*)(wab + (size_t)colw * 128 + kc * 32 + quad * 8);
        WRf[kc] = *(const bf16x8*)(wrb + (size_t)colw * 128 + kc * 32 + quad * 8);
        WSf[kc] = *(const bf16x8*)(wsb + (size_t)colw * 128 + kc * 32 + quad * 8);
    }
    float ppbc = ppb[colw];
    int es = t >> 3, cs2 = (t & 7) * 2;
    int egs = es >> 4, ms = es & 15;
    const int NTL = N_P / 64;
    for (int tile = blockIdx.x; tile < NTL; tile += gridDim.x) {
        long base = (long)tile * 64;
        __syncthreads();                       // prev tile's BUFB reads done
        // stage agg -> BUFA (frag layout)
        #pragma unroll
        for (int ci = 0; ci < 2; ci++) {
            int kq = cs2 + ci;
            const float* src = agg + (base + es) * 128 + kq * 8;
            float4 f0 = *(const float4*)src, f1 = *(const float4*)(src + 4);
            uint4 v;
            v.x = pk2(f0.x, f0.y); v.y = pk2(f0.z, f0.w);
            v.z = pk2(f1.x, f1.y); v.w = pk2(f1.z, f1.w);
            *(uint4*)&BUFA[((egs * 16 + kq) * 16 + ms) * 8] = v;
        }
        bar_l();                               // BUFA visible
        // eff = relu(Wa@agg + T + ppb) -> BUFB (frag layout)
        {
            f32x4 acc[4] = {};
            #pragma unroll
            for (int eg = 0; eg < 4; eg++)
                #pragma unroll
                for (int kc = 0; kc < 4; kc++) {
                    bf16x8 af = *(const bf16x8*)&BUFA[((eg * 16 + kc * 4 + quad) * 16 + mm) * 8];
                    acc[eg] = MFMA(af, WAf[kc], acc[eg]);
                }
            #pragma unroll
            for (int eg = 0; eg < 4; eg++)
                #pragma unroll
                for (int rg = 0; rg < 4; rg++) {
                    long row = base + eg * 16 + quad * 4 + rg;
                    float v = acc[eg][rg] + b2f(T[row * 128 + colw]) + ppbc;
                    BUFB[((eg * 16 + (colw >> 3)) * 16 + quad * 4 + rg) * 8 + (colw & 7)] =
                        f2b(fmaxf(v, 0.f));
                }
        }
        bar_l();                               // BUFB visible, BUFA reads done
        // U = Wr@eff, V = Ws@eff (single pass over BUFB)
        {
            f32x4 au[4] = {}, av[4] = {};
            #pragma unroll
            for (int eg = 0; eg < 4; eg++)
                #pragma unroll
                for (int kc = 0; kc < 4; kc++) {
                    bf16x8 af = *(const bf16x8*)&BUFB[((eg * 16 + kc * 4 + quad) * 16 + mm) * 8];
                    au[eg] = MFMA(af, WRf[kc], au[eg]);
                    av[eg] = MFMA(af, WSf[kc], av[eg]);
                }
            #pragma unroll
            for (int eg = 0; eg < 4; eg++)
                #pragma unroll
                for (int rg = 0; rg < 4; rg++) {
                    long row = base + eg * 16 + quad * 4 + rg;
                    U[row * 128 + colw] = f2b(au[eg][rg]);
                    V[row * 128 + colw] = f2b(av[eg][rg]);
                }
        }
    }
}

// ================= node update step 2 (col-split) + fused fluid MLP + rigid pool ====
__global__ __launch_bounds__(512, 4) void k_node2fl(
        const float* __restrict__ agg, const u16* __restrict__ T,
        const u16* __restrict__ wab, const float* __restrict__ ppb,
        float* __restrict__ pooledsum,
        const u16* __restrict__ w0b, const float* __restrict__ b0,
        const u16* __restrict__ w1b, const float* __restrict__ b1,
        const u16* __restrict__ w2b, const float* __restrict__ b2,
        float* __restrict__ out) {
    __shared__ __align__(16) u16 BUFA[64 * 128];
    __shared__ __align__(16) u16 BUFB[64 * 128];
    int t = threadIdx.x;
    int w = t >> 6, lane = t & 63, mm = lane & 15, quad = lane >> 4;
    int colw = w * 16 + mm;
    bf16x8 WAf[4], W0f[4], W1f[4];
    #pragma unroll
    for (int kc = 0; kc < 4; kc++) {
        WAf[kc] = *(const bf16x8*)(wab + (size_t)colw * 128 + kc * 32 + quad * 8);
        W0f[kc] = *(const bf16x8*)(w0b + (size_t)colw * 128 + kc * 32 + quad * 8);
        W1f[kc] = *(const bf16x8*)(w1b + (size_t)colw * 128 + kc * 32 + quad * 8);
    }
    float ppbc = ppb[colw], b0c = b0[colw], b1c = b1[colw];
    int es = t >> 3, cs2 = (t & 7) * 2;
    int egs = es >> 4, ms = es & 15;
    const int NTL = N_P / 64;
    for (int tile = blockIdx.x; tile < NTL; tile += gridDim.x) {
        long base = (long)tile * 64;
        bool fluid = base >= RIG_;
        bar_l();                               // prev tile's BUF reads done
        // stage agg -> BUFA (frag layout)
        #pragma unroll
        for (int ci = 0; ci < 2; ci++) {
            int kq = cs2 + ci;
            const float* src = agg + (base + es) * 128 + kq * 8;
            float4 f0 = *(const float4*)src, f1 = *(const float4*)(src + 4);
            uint4 v;
            v.x = pk2(f0.x, f0.y); v.y = pk2(f0.z, f0.w);
            v.z = pk2(f1.x, f1.y); v.w = pk2(f1.z, f1.w);
            *(uint4*)&BUFA[((egs * 16 + kq) * 16 + ms) * 8] = v;
        }
        bar_l();                               // BUFA visible
        // eff = relu(Wa@agg + T + ppb)
        f32x4 acc[4] = {};
        #pragma unroll
        for (int eg = 0; eg < 4; eg++)
            #pragma unroll
            for (int kc = 0; kc < 4; kc++) {
                bf16x8 af = *(const bf16x8*)&BUFA[((eg * 16 + kc * 4 + quad) * 16 + mm) * 8];
                acc[eg] = MFMA(af, WAf[kc], acc[eg]);
            }
        if (!fluid) {
            // rigid: per-lane col partial sum over its 16 rows, reduce across quads
            float s = 0.f;
            #pragma unroll
            for (int eg = 0; eg < 4; eg++)
                #pragma unroll
                for (int rg = 0; rg < 4; rg++) {
                    long row = base + eg * 16 + quad * 4 + rg;
                    float v = acc[eg][rg] + b2f(T[row * 128 + colw]) + ppbc;
                    s += b2f(f2b(fmaxf(v, 0.f)));
                }
            s += __shfl_xor(s, 16);
            s += __shfl_xor(s, 32);
            if (quad == 0) atomicAdd(&pooledsum[colw], s);
            continue;                          // block-uniform
        }
        #pragma unroll
        for (int eg = 0; eg < 4; eg++)
            #pragma unroll
            for (int rg = 0; rg < 4; rg++) {
                long row = base + eg * 16 + quad * 4 + rg;
                float v = acc[eg][rg] + b2f(T[row * 128 + colw]) + ppbc;
                BUFB[((eg * 16 + (colw >> 3)) * 16 + quad * 4 + rg) * 8 + (colw & 7)] =
                    f2b(fmaxf(v, 0.f));
            }
        bar_l();                               // BUFB visible, BUFA reads done
        // fluid L0: BUFB -> BUFA
        {
            f32x4 a[4] = {};
            #pragma unroll
            for (int eg = 0; eg < 4; eg++)
                #pragma unroll
                for (int kc = 0; kc < 4; kc++) {
                    bf16x8 af = *(const bf16x8*)&BUFB[((eg * 16 + kc * 4 + quad) * 16 + mm) * 8];
                    a[eg] = MFMA(af, W0f[kc], a[eg]);
                }
            #pragma unroll
            for (int eg = 0; eg < 4; eg++)
                #pragma unroll
                for (int rg = 0; rg < 4; rg++)
                    BUFA[((eg * 16 + (colw >> 3)) * 16 + quad * 4 + rg) * 8 + (colw & 7)] =
                        f2b(fmaxf(a[eg][rg] + b0c, 0.f));
        }
        bar_l();                               // BUFA visible, BUFB reads done
        // fluid L1: BUFA -> BUFB
        {
            f32x4 a[4] = {};
            #pragma unroll
            for (int eg = 0; eg < 4; eg++)
                #pragma unroll
                for (int kc = 0; kc < 4; kc++) {
                    bf16x8 af = *(const bf16x8*)&BUFA[((eg * 16 + kc * 4 + quad) * 16 + mm) * 8];
                    a[eg] = MFMA(af, W1f[kc], a[eg]);
                }
            #pragma unroll
            for (int eg = 0; eg < 4; eg++)
                #pragma unroll
                for (int rg = 0; rg < 4; rg++)
                    BUFB[((eg * 16 + (colw >> 3)) * 16 + quad * 4 + rg) * 8 + (colw & 7)] =
                        f2b(fmaxf(a[eg][rg] + b1c, 0.f));
        }
        bar_l();                               // BUFB visible
        // fluid L2 -> out: waves 0-3 handle row-tiles 0-3 (w2b streamed, 4KB)
        if (w < 4) {
            f32x4 a1 = {};
            #pragma unroll
            for (int kc = 0; kc < 4; kc++) {
                bf16x8 af = *(const bf16x8*)&BUFB[((w * 16 + kc * 4 + quad) * 16 + mm) * 8];
                bf16x8 bf = *(const bf16x8*)(w2b + (size_t)mm * 128 + kc * 32 + quad * 8);
                a1 = MFMA(af, bf, a1);
            }
            if (mm < 3) {
                float bv = b2[mm];
                #pragma unroll
                for (int rg = 0; rg < 4; rg++) {
                    long row = base + w * 16 + quad * 4 + rg;
                    out[row * 3 + mm] = a1[rg] + bv;
                }
            }
        }
    }
}

// ================= step-2 edge (persistent, pipelined): relu(Z+U[rv]+V[sv]+b) -> segsum ==
__global__ __launch_bounds__(512, 4) void k_edge2(
        const u16* __restrict__ Z, const u16* __restrict__ U, const u16* __restrict__ V,
        const int4* __restrict__ edges,
        const float* __restrict__ rpb, float* __restrict__ agg) {
    __shared__ __align__(16) u16 S16[2][64 * 136];
    __shared__ int rv_s[2][64];
    __shared__ float rpb_s[128];
    int t = threadIdx.x;
    if (t < 128) rpb_s[t] = rpb[t];
    int ec = t >> 3, cc = (t & 7) * 16;       // edge, col-chunk base
    int sseg = t >> 7, cseg = t & 127;        // segsum mapping (4 strips of 16)
    const long NT = N_E / 64;
    const long stride = gridDim.x;

    long tile = blockIdx.x;
    // prefetch first tile's rows
    uint4 zC0, zC1, uC0, uC1, vC0, vC1; int rvC;
    {
        long nb = tile * 64;
        int4 e = edges[nb + ec];
        rvC = edges[nb + (t & 63)].x;
        const u16* zp = Z + (nb + ec) * 128 + cc;
        zC0 = *(const uint4*)zp; zC1 = *(const uint4*)(zp + 8);
        const u16* up = U + (size_t)e.x * 128 + cc;
        uC0 = *(const uint4*)up; uC1 = *(const uint4*)(up + 8);
        const u16* vp = V + (size_t)e.y * 128 + cc;
        vC0 = *(const uint4*)vp; vC1 = *(const uint4*)(vp + 8);
    }
    __syncthreads();                           // rpb_s visible
    int p = 0;
    for (; tile < NT; tile += stride) {
        long ntile = tile + stride;
        bool hn = ntile < NT;
        if (t < 64) rv_s[p][t] = rvC;
        // stage relu(z + u + v + rpb) -> S16[p] from prefetched registers
        {
            const u16* zz = (const u16*)&zC0; const u16* uu = (const u16*)&uC0;
            const u16* vv = (const u16*)&vC0;
            u16 o[8];
            #pragma unroll
            for (int j = 0; j < 8; j++)
                o[j] = f2b(fmaxf(b2f(zz[j]) + b2f(uu[j]) + b2f(vv[j]) + rpb_s[cc + j], 0.f));
            *(uint4*)&S16[p][ec * 136 + cc] = *(uint4*)o;
            zz = (const u16*)&zC1; uu = (const u16*)&uC1; vv = (const u16*)&vC1;
            #pragma unroll
            for (int j = 0; j < 8; j++)
                o[j] = f2b(fmaxf(b2f(zz[j]) + b2f(uu[j]) + b2f(vv[j]) + rpb_s[cc + 8 + j], 0.f));
            *(uint4*)&S16[p][ec * 136 + cc + 8] = *(uint4*)o;
        }
        // next tile's loads: in flight across the barrier + segsum
        uint4 zN0{}, zN1{}, uN0{}, uN1{}, vN0{}, vN1{}; int rvN = 0;
        if (hn) {
            long nb = ntile * 64;
            int4 e = edges[nb + ec];
            rvN = edges[nb + (t & 63)].x;
            const u16* zp = Z + (nb + ec) * 128 + cc;
            zN0 = *(const uint4*)zp; zN1 = *(const uint4*)(zp + 8);
            const u16* up = U + (size_t)e.x * 128 + cc;
            uN0 = *(const uint4*)up; uN1 = *(const uint4*)(up + 8);
            const u16* vp = V + (size_t)e.y * 128 + cc;
            vN0 = *(const uint4*)vp; vN1 = *(const uint4*)(vp + 8);
        }
        bar_l();                               // S16[p] + rv_s[p] visible
        // run-length segmented sum; interior runs -> plain store
        {
            int r0 = sseg * 16;
            int cur = rv_s[p][r0];
            float a = b2f(S16[p][r0 * 136 + cseg]);
            bool first = true;
            for (int rr = r0 + 1; rr < r0 + 16; rr++) {
                int n = rv_s[p][rr];
                float v = b2f(S16[p][rr * 136 + cseg]);
                if (n == cur) a += v;
                else {
                    if (first) atomicAdd(&agg[(size_t)cur * 128 + cseg], a);
                    else       agg[(size_t)cur * 128 + cseg] = a;
                    first = false; cur = n; a = v;
                }
            }
            atomicAdd(&agg[(size_t)cur * 128 + cseg], a);
        }
        // rotate prefetched rows
        if (hn) { zC0 = zN0; zC1 = zN1; uC0 = uN0; uC1 = uN1; vC0 = vN0; vC1 = vN1; rvC = rvN; }
        p ^= 1;
    }
}

// ================= rigid head (pooled = sum/RIG) =================
__global__ __launch_bounds__(128) void k_rigid_head(
        const float* __restrict__ pooledsum,
        const float* __restrict__ w0, const float* __restrict__ b0,
        const float* __restrict__ w1, const float* __restrict__ b1,
        const float* __restrict__ w2, const float* __restrict__ b2,
        float* __restrict__ rig) {
    __shared__ float pl[128], ha[128], hb[128], tv[7];
    int t = threadIdx.x;
    pl[t] = pooledsum[t] * (1.0f / (float)RIG_);
    __syncthreads();
    float a = b0[t];
    for (int k = 0; k < 128; k++) a += w0[t * 128 + k] * pl[k];
    ha[t] = fmaxf(a, 0.f);
    __syncthreads();
    a = b1[t];
    for (int k = 0; k < 128; k++) a += w1[t * 128 + k] * ha[k];
    hb[t] = fmaxf(a, 0.f);
    __syncthreads();
    if (t < 7) {
        float s = b2[t];
        for (int k = 0; k < 128; k++) s += w2[t * 128 + k] * hb[k];
        tv[t] = s;
    }
    __syncthreads();
    if (t == 0) {
        float w = tv[0], x = tv[1], y = tv[2], z = tv[3];
        float n = sqrtf(w * w + x * x + y * y + z * z);
        w /= n; x /= n; y /= n; z /= n;
        rig[0] = 1.f - 2.f * (y * y + z * z); rig[1] = 2.f * (x * y + z * w); rig[2] = 2.f * (x * z - y * w);
        rig[3] = 2.f * (x * y - z * w); rig[4] = 1.f - 2.f * (x * x + z * z); rig[5] = 2.f * (y * z + x * w);
        rig[6] = 2.f * (x * z + y * w); rig[7] = 2.f * (y * z - x * w); rig[8] = 1.f - 2.f * (x * x + y * y);
        rig[9] = tv[4]; rig[10] = tv[5]; rig[11] = tv[6];
    }
}

// ================= rigid output =================
__global__ __launch_bounds__(256) void k_rigid_out(
        const float* __restrict__ state, const float* __restrict__ cent,
        const float* __restrict__ rig, float* __restrict__ out) {
    int i = blockIdx.x * 256 + threadIdx.x;
    if (i >= RIG_) return;
    float p0[3], d[3];
    #pragma unroll
    for (int k = 0; k < 3; k++) { p0[k] = state[i * 6 + k]; d[k] = p0[k] - cent[k]; }
    #pragma unroll
    for (int j = 0; j < 3; j++) {
        float p1 = rig[0 * 3 + j] * d[0] + rig[1 * 3 + j] * d[1] + rig[2 * 3 + j] * d[2]
                 + rig[9 + j] + cent[j];
        out[i * 3 + j] = (p1 - p0[j]) * 60.0f;
    }
}

// ================= host =================
extern "C" void kernel_launch(void* const* d_in, const int* in_sizes, int n_in,
                              void* d_out, int out_size, void* d_ws, size_t ws_size,
                              hipStream_t stream) {
    const float* state = (const float*)d_in[0];
    const float* attr  = (const float*)d_in[1];
    const float* Ra    = (const float*)d_in[2];
    const int*   recv  = (const int*)d_in[3];
    const int*   send  = (const int*)d_in[4];
    const float* pe_w0 = (const float*)d_in[5];  const float* pe_b0 = (const float*)d_in[6];
    const float* pe_w1 = (const float*)d_in[7];  const float* pe_b1 = (const float*)d_in[8];
    const float* re_w0 = (const float*)d_in[9];  const float* re_b0 = (const float*)d_in[10];
    const float* re_w1 = (const float*)d_in[11]; const float* re_b1 = (const float*)d_in[12];
    const float* re_w2 = (const float*)d_in[13]; const float* re_b2 = (const float*)d_in[14];
    const float* rp_w  = (const float*)d_in[15]; const float* rp_b  = (const float*)d_in[16];
    const float* pp_w  = (const float*)d_in[17]; const float* pp_b  = (const float*)d_in[18];
    const float* rg_w0 = (const float*)d_in[19]; const float* rg_b0 = (const float*)d_in[20];
    const float* rg_w1 = (const float*)d_in[21]; const float* rg_b1 = (const float*)d_in[22];
    const float* rg_w2 = (const float*)d_in[23]; const float* rg_b2 = (const float*)d_in[24];
    const float* fl_w0 = (const float*)d_in[25]; const float* fl_b0 = (const float*)d_in[26];
    const float* fl_w1 = (const float*)d_in[27]; const float* fl_b1 = (const float*)d_in[28];
    const float* fl_w2 = (const float*)d_in[29]; const float* fl_b2 = (const float*)d_in[30];
    float* out = (float*)d_out;

    // ---- workspace carve-out ----
    char* p = (char*)d_ws;
    auto alloc = [&](size_t bytes) { char* r = p; p += (bytes + 255) / 256 * 256; return r; };
    float* cent    = (float*)alloc(8 * 4);
    float* pooled  = (float*)alloc(128 * 4);
    float* rig     = (float*)alloc(16 * 4);
    u32*   rowhead = (u32*)alloc((size_t)N_P * 4);
    u32*   bsum    = (u32*)alloc(256 * 4);
    int4*  edges   = (int4*)alloc((size_t)N_E * 16);
    float* agg     = (float*)alloc((size_t)N_P * 128 * 4);
    u16*   Z       = (u16*)alloc((size_t)N_E * 128 * 2);
    u16*   T       = (u16*)alloc((size_t)N_P * 128 * 2);
    u16*   P       = (u16*)alloc((size_t)N_P * 128 * 2);   // aliased as U after k_rel
    u16*   Q       = (u16*)alloc((size_t)N_P * 128 * 2);   // aliased as V after k_rel
    u16*   wreb    = (u16*)alloc(128 * 128 * 2);
    u16*   wrb     = (u16*)alloc(128 * 128 * 2);
    u16*   wsb     = (u16*)alloc(128 * 128 * 2);
    u16*   wpb     = (u16*)alloc(128 * 128 * 2);
    u16*   wab     = (u16*)alloc(128 * 128 * 2);
    u16*   rw1b    = (u16*)alloc(128 * 128 * 2);
    u16*   rw2b    = (u16*)alloc(128 * 128 * 2);
    u16*   pew1b   = (u16*)alloc(128 * 128 * 2);
    u16*   flw0b   = (u16*)alloc(128 * 128 * 2);
    u16*   flw1b   = (u16*)alloc(128 * 128 * 2);
    u16*   flw2b   = (u16*)alloc(16 * 128 * 2);
    u16*   w0rb    = (u16*)alloc(128 * 32 * 2);
    u16*   w0sb    = (u16*)alloc(128 * 32 * 2);
    u16*   pew0b   = (u16*)alloc(128 * 32 * 2);
    size_t need = (size_t)(p - (char*)d_ws);
    if (ws_size < need) {
        fprintf(stderr, "kernel_launch: ws_size %zu < needed %zu\n", ws_size, need);
        return;
    }
    u16* U = P; u16* V = Q;

    // ---- sort edges by recv ----
    hipMemsetAsync(rowhead, 0, (size_t)N_P * 4, stream);
    k_hist<<<N_E / 256, 256, 0, stream>>>(recv, rowhead);
    k_scan1<<<N_P / 256, 256, 0, stream>>>(rowhead, bsum);
    k_scan2<<<1, 256, 0, stream>>>(bsum);
    k_scan3<<<N_P / 256, 256, 0, stream>>>(rowhead, bsum);
    k_scatter<<<N_E / 256, 256, 0, stream>>>(recv, send, Ra, rowhead, edges);

    // ---- weight conversion ----
    CvtArgs ca;
    int bs = 0;
    auto addjob = [&](int idx, const float* s, u16* d, int n, int mode) {
        ca.j[idx] = {s, d, n, mode, bs};
        bs += (n + 255) / 256;
    };
    addjob(0,  rp_w,        wreb,  128 * 128, 3);
    addjob(1,  rp_w + 128,  wrb,   128 * 128, 3);
    addjob(2,  rp_w + 256,  wsb,   128 * 128, 3);
    addjob(3,  pp_w,        wpb,   128 * 128, 4);
    addjob(4,  pp_w + 128,  wab,   128 * 128, 4);
    addjob(5,  re_w1,       rw1b,  128 * 128, 0);
    addjob(6,  re_w2,       rw2b,  128 * 128, 0);
    addjob(7,  pe_w1,       pew1b, 128 * 128, 0);
    addjob(8,  fl_w0,       flw0b, 128 * 128, 0);
    addjob(9,  fl_w1,       flw1b, 128 * 128, 0);
    addjob(10, fl_w2,       flw2b, 16 * 128,  2);
    addjob(11, re_w0,       w0rb,  128 * 32,  5);
    addjob(12, re_w0,       w0sb,  128 * 32,  6);
    addjob(13, pe_w0,       pew0b, 128 * 32,  7);
    k_cvt_all<<<bs, 256, 0, stream>>>(ca);

    // ---- encoders ----
    k_centroid<<<6, 256, 0, stream>>>(state, cent);
    k_particle_ext<<<512, 512, 0, stream>>>(state, attr, cent,
                                            w0rb, w0sb, pew0b, pe_b0,
                                            pew1b, pe_b1, wpb, P, Q, T);

    // ---- step 1: rel-enc + Z + fused agg ----
    hipMemsetAsync(agg, 0, (size_t)N_P * 128 * 4, stream);
    k_rel<<<512, 512, 0, stream>>>(P, Q, edges,
                                   re_w0, re_b0, rw1b, re_b1, rw2b, re_b2,
                                   wreb, rp_b, Z, agg);
    // node update fused with U/V production (col-split, persistent)
    k_node2<<<512, 512, 0, stream>>>(agg, T, wab, pp_b, wrb, wsb, U, V);

    // ---- step 2 ----
    hipMemsetAsync(agg, 0, (size_t)N_P * 128 * 4, stream);
    hipMemsetAsync(pooled, 0, 128 * 4, stream);
    k_edge2<<<512, 512, 0, stream>>>(Z, U, V, edges, rp_b, agg);
    // node update fused with fluid MLP + rigid pooled accumulation (col-split)
    k_node2fl<<<512, 512, 0, stream>>>(agg, T, wab, pp_b, pooled,
                                       flw0b, fl_b0, flw1b, fl_b1,
                                       flw2b, fl_b2, out);

    // ---- heads (rigid) ----
    k_rigid_head<<<1, 128, 0, stream>>>(pooled, rg_w0, rg_b0, rg_w1, rg_b1, rg_w2, rg_b2, rig);
    k_rigid_out<<<(RIG_ + 255) / 256, 256, 0, stream>>>(state, cent, rig, out);
}

// Round 14
// 456.838 us; speedup vs baseline: 1.0209x; 1.0156x over previous
//
#include <hip/hip_runtime.h>
#include <hip/hip_bf16.h>
#include <cstdio>

#define N_P   65536
#define N_E   524288
#define RIG_  4096

typedef __attribute__((ext_vector_type(8))) short bf16x8;
typedef __attribute__((ext_vector_type(4))) float f32x4;
typedef __attribute__((ext_vector_type(4))) unsigned int u32x4;
typedef unsigned short u16;
typedef unsigned int   u32;

__device__ __forceinline__ u16 f2b(float x) {
    __hip_bfloat16 h = __float2bfloat16(x);
    return *(u16*)&h;
}
__device__ __forceinline__ float b2f(u16 u) {
    union { unsigned u; float f; } c; c.u = ((unsigned)u) << 16; return c.f;
}
__device__ __forceinline__ unsigned pk2(float x, float y) {
    return (unsigned)f2b(x) | ((unsigned)f2b(y) << 16);
}
#define MFMA(a,b,c) __builtin_amdgcn_mfma_f32_16x16x32_bf16((a),(b),(c),0,0,0)

// NOTE r12 lesson: XOR bank-swizzle on the frag tiles cut SQ_LDS_BANK_CONFLICT
// 4x but REGRESSED total (+1%): conflicts were TLP-hidden, the extra address
// VALU was not. Linear frag layout restored. DO NOT RE-SWIZZLE.

// LDS-only barrier: waits LDS ops, does NOT drain global stores/atomics.
__device__ __forceinline__ void bar_l() {
    asm volatile("s_waitcnt lgkmcnt(0)\n\ts_barrier" ::: "memory");
}

// ================= sort: histogram / scan / scatter =================
__global__ __launch_bounds__(256) void k_hist(const int* __restrict__ recv,
                                              u32* __restrict__ cnt) {
    int i = blockIdx.x * 256 + threadIdx.x;
    if (i < N_E) atomicAdd(&cnt[recv[i]], 1u);
}
__global__ __launch_bounds__(256) void k_scan1(u32* __restrict__ data,
                                               u32* __restrict__ bsum) {
    __shared__ u32 s[256];
    int t = threadIdx.x, g = blockIdx.x * 256 + t;
    u32 v = data[g];
    s[t] = v; __syncthreads();
    for (int o = 1; o < 256; o <<= 1) {
        u32 x = (t >= o) ? s[t - o] : 0u;
        __syncthreads(); s[t] += x; __syncthreads();
    }
    data[g] = s[t] - v;
    if (t == 255) bsum[blockIdx.x] = s[255];
}
__global__ __launch_bounds__(256) void k_scan2(u32* __restrict__ bsum) {
    __shared__ u32 s[256];
    int t = threadIdx.x;
    u32 v = bsum[t];
    s[t] = v; __syncthreads();
    for (int o = 1; o < 256; o <<= 1) {
        u32 x = (t >= o) ? s[t - o] : 0u;
        __syncthreads(); s[t] += x; __syncthreads();
    }
    bsum[t] = s[t] - v;
}
__global__ __launch_bounds__(256) void k_scan3(u32* __restrict__ data,
                                               const u32* __restrict__ bsum) {
    int g = blockIdx.x * 256 + threadIdx.x;
    data[g] += bsum[blockIdx.x];
}
// packed edge record: {recv, send, Ra_bits, pad} -> one 16B store per edge.
__global__ __launch_bounds__(256) void k_scatter(const int* __restrict__ recv,
                                                 const int* __restrict__ send,
                                                 const float* __restrict__ Ra,
                                                 u32* __restrict__ head,
                                                 int4* __restrict__ edges) {
    int i = blockIdx.x * 256 + threadIdx.x;
    if (i < N_E) {
        int n = recv[i];
        u32 pos = atomicAdd(&head[n], 1u);
        edges[pos] = make_int4(n, send[i], __float_as_int(Ra[i]), 0);
    }
}

// ================= fused weight conversion =================
// modes: 0 plain; 2 pad-rows [3][128]->[16][128]; 3 col-slice stride 384;
// 4 col-slice stride 256; 5 W0r-select; 6 W0s-select; 7 pad15->32
struct CvtJob { const float* src; u16* dst; int n; int mode; int bstart; };
struct CvtArgs { CvtJob j[14]; };

__global__ __launch_bounds__(256) void k_cvt_all(CvtArgs a) {
    int b = blockIdx.x;
    int ji = 0;
    #pragma unroll
    for (int k = 1; k < 14; k++) if (b >= a.j[k].bstart) ji = k;
    CvtJob jb = a.j[ji];
    int i = (b - jb.bstart) * 256 + threadIdx.x;
    if (i >= jb.n) return;
    if (jb.mode == 0) {
        jb.dst[i] = f2b(jb.src[i]);
    } else if (jb.mode == 2) {
        int r = i >> 7;
        jb.dst[i] = (r < 3) ? f2b(jb.src[i]) : 0;
    } else if (jb.mode == 3) {
        int r = i >> 7, c = i & 127;
        jb.dst[i] = f2b(jb.src[r * 384 + c]);
    } else if (jb.mode == 4) {
        int r = i >> 7, c = i & 127;
        jb.dst[i] = f2b(jb.src[r * 256 + c]);
    } else if (jb.mode == 5) {               // W0r: [attr2_r(9), state_r(6)] cols
        int r = i >> 5, c = i & 31;
        float v = 0.f;
        if (c < 9)       v = jb.src[r * 31 + c];
        else if (c < 15) v = jb.src[r * 31 + 18 + (c - 9)];
        jb.dst[i] = f2b(v);
    } else if (jb.mode == 6) {               // W0s: [attr2_s(9), state_s(6)] cols
        int r = i >> 5, c = i & 31;
        float v = 0.f;
        if (c < 9)       v = jb.src[r * 31 + 9 + c];
        else if (c < 15) v = jb.src[r * 31 + 24 + (c - 9)];
        jb.dst[i] = f2b(v);
    } else {                                  // mode 7: [128][15] -> [128][32]
        int r = i >> 5, c = i & 31;
        jb.dst[i] = (c < 15) ? f2b(jb.src[r * 15 + c]) : 0;
    }
}

// ================= centroid =================
__global__ __launch_bounds__(256) void k_centroid(const float* __restrict__ state,
                                                  float* __restrict__ cent) {
    int d = blockIdx.x;
    __shared__ float red[256];
    float s = 0.f;
    for (int r = threadIdx.x; r < RIG_; r += 256) s += state[r * 6 + d];
    red[threadIdx.x] = s; __syncthreads();
    for (int o = 128; o > 0; o >>= 1) {
        if (threadIdx.x < o) red[threadIdx.x] += red[threadIdx.x + o];
        __syncthreads();
    }
    if (threadIdx.x == 0) cent[d] = red[0] / (float)RIG_;
}

// ================= particle (col-split, persistent): feat(15) -> {P, Q, pe MLP, T} =====
__global__ __launch_bounds__(512, 4) void k_particle_ext(
        const float* __restrict__ state, const float* __restrict__ attr,
        const float* __restrict__ cent,
        const u16* __restrict__ w0r, const u16* __restrict__ w0s,   // [128][32]
        const u16* __restrict__ pew0, const float* __restrict__ pe_b0, // [128][32]
        const u16* __restrict__ pew1, const float* __restrict__ pe_b1, // [128][128]
        const u16* __restrict__ wp,                                    // [128][128]
        u16* __restrict__ P, u16* __restrict__ Q, u16* __restrict__ T) {
    __shared__ float in_s[64][16];
    __shared__ u16 INF[64 * 32];
    __shared__ __align__(16) u16 BUFA[64 * 128];
    __shared__ __align__(16) u16 BUFB[64 * 128];
    int t = threadIdx.x;
    int w = t >> 6, lane = t & 63, mm = lane & 15, quad = lane >> 4;
    int colw = w * 16 + mm;
    bf16x8 W0Rf = *(const bf16x8*)(w0r  + (size_t)colw * 32 + quad * 8);
    bf16x8 W0Sf = *(const bf16x8*)(w0s  + (size_t)colw * 32 + quad * 8);
    bf16x8 PE0f = *(const bf16x8*)(pew0 + (size_t)colw * 32 + quad * 8);
    bf16x8 PE1f[4], WPf[4];
    #pragma unroll
    for (int kc = 0; kc < 4; kc++) {
        PE1f[kc] = *(const bf16x8*)(pew1 + (size_t)colw * 128 + kc * 32 + quad * 8);
        WPf[kc]  = *(const bf16x8*)(wp   + (size_t)colw * 128 + kc * 32 + quad * 8);
    }
    float b0c = pe_b0[colw], b1c = pe_b1[colw];
    const int NTL = N_P / 64;
    for (int tile = blockIdx.x; tile < NTL; tile += gridDim.x) {
        int base = tile * 64;
        bar_l();                              // prev tile's INF/BUFB reads done
        // stage feat(15) -> in_s
        for (int it = t; it < 64 * 15; it += 512) {
            int r = it / 15, c = it % 15;
            int p = base + r;
            float v;
            if (c < 3)      v = attr[p * 3 + c];
            else if (c < 9) v = (p < RIG_) ? (state[p * 6 + (c - 3)] - cent[c - 3]) : 0.0f;
            else            v = state[p * 6 + (c - 9)];
            in_s[r][c] = v;
        }
        bar_l();                              // in_s visible
        // pack INF frags (first 256 threads cover 64x32)
        if (t < 256) {
            int wv = t >> 6, kq4 = (t >> 4) & 3, m = t & 15;
            int e = wv * 16 + m;
            u16 tmp[8];
            #pragma unroll
            for (int j = 0; j < 8; j++) {
                int k = kq4 * 8 + j;
                tmp[j] = (k < 15) ? f2b(in_s[e][k]) : (u16)0;
            }
            *(uint4*)&INF[((wv * 4 + kq4) * 16 + m) * 8] = *(uint4*)tmp;
        }
        bar_l();                              // INF visible
        bf16x8 af0[4];
        #pragma unroll
        for (int eg = 0; eg < 4; eg++)
            af0[eg] = *(const bf16x8*)&INF[((eg * 4 + quad) * 16 + mm) * 8];
        // P = W0r @ feat
        {
            f32x4 a[4] = {};
            #pragma unroll
            for (int eg = 0; eg < 4; eg++) a[eg] = MFMA(af0[eg], W0Rf, a[eg]);
            #pragma unroll
            for (int eg = 0; eg < 4; eg++)
                #pragma unroll
                for (int rg = 0; rg < 4; rg++)
                    P[(size_t)(base + eg * 16 + quad * 4 + rg) * 128 + colw] = f2b(a[eg][rg]);
        }
        // Q = W0s @ feat
        {
            f32x4 a[4] = {};
            #pragma unroll
            for (int eg = 0; eg < 4; eg++) a[eg] = MFMA(af0[eg], W0Sf, a[eg]);
            #pragma unroll
            for (int eg = 0; eg < 4; eg++)
                #pragma unroll
                for (int rg = 0; rg < 4; rg++)
                    Q[(size_t)(base + eg * 16 + quad * 4 + rg) * 128 + colw] = f2b(a[eg][rg]);
        }
        // pe L1 -> BUFA (frag)
        {
            f32x4 a[4] = {};
            #pragma unroll
            for (int eg = 0; eg < 4; eg++) a[eg] = MFMA(af0[eg], PE0f, a[eg]);
            #pragma unroll
            for (int eg = 0; eg < 4; eg++)
                #pragma unroll
                for (int rg = 0; rg < 4; rg++)
                    BUFA[((eg * 16 + (colw >> 3)) * 16 + quad * 4 + rg) * 8 + (colw & 7)] =
                        f2b(fmaxf(a[eg][rg] + b0c, 0.f));
        }
        bar_l();                              // BUFA visible
        // pe L2 -> BUFB (frag)
        {
            f32x4 a[4] = {};
            #pragma unroll
            for (int eg = 0; eg < 4; eg++)
                #pragma unroll
                for (int kc = 0; kc < 4; kc++) {
                    bf16x8 af = *(const bf16x8*)&BUFA[((eg * 16 + kc * 4 + quad) * 16 + mm) * 8];
                    a[eg] = MFMA(af, PE1f[kc], a[eg]);
                }
            #pragma unroll
            for (int eg = 0; eg < 4; eg++)
                #pragma unroll
                for (int rg = 0; rg < 4; rg++)
                    BUFB[((eg * 16 + (colw >> 3)) * 16 + quad * 4 + rg) * 8 + (colw & 7)] =
                        f2b(fmaxf(a[eg][rg] + b1c, 0.f));
        }
        bar_l();                              // BUFB visible, BUFA reads done
        // T = Wp @ particle_encode
        {
            f32x4 a[4] = {};
            #pragma unroll
            for (int eg = 0; eg < 4; eg++)
                #pragma unroll
                for (int kc = 0; kc < 4; kc++) {
                    bf16x8 af = *(const bf16x8*)&BUFB[((eg * 16 + kc * 4 + quad) * 16 + mm) * 8];
                    a[eg] = MFMA(af, WPf[kc], a[eg]);
                }
            #pragma unroll
            for (int eg = 0; eg < 4; eg++)
                #pragma unroll
                for (int rg = 0; rg < 4; rg++)
                    T[(size_t)(base + eg * 16 + quad * 4 + rg) * 128 + colw] = f2b(a[eg][rg]);
        }
    }
}

// ================= relation (col-split, reg weights, dbuf, light barriers) ========
// 12 frags / 64 VGPR / 2 blocks/CU is the feasible optimum (r6/r8 proved the
// allocator refuses more resident weight frags). DO NOT RAISE.
// Z stores are NON-TEMPORAL: Z (128MB) is write-once/read-once streaming; keep
// it out of L2 so the P/Q gather set (32MB) stays resident.
__global__ __launch_bounds__(512, 4) void k_rel(
        const u16* __restrict__ P, const u16* __restrict__ Q,
        const int4* __restrict__ edges,
        const float* __restrict__ re_w0_raw, const float* __restrict__ b0,
        const u16* __restrict__ w1b, const float* __restrict__ b1,
        const u16* __restrict__ w2b, const float* __restrict__ b2,
        const u16* __restrict__ wreb, const float* __restrict__ rpb,
        u16* __restrict__ Z, float* __restrict__ agg) {
    __shared__ __align__(16) u16 BUFA[64 * 136];
    __shared__ __align__(16) u16 BUFB[64 * 136];
    __shared__ int rv_s[2][64];
    __shared__ float wRa_s[128], b0_s[128], rpb_s[128];
    int t = threadIdx.x;
    if (t < 128) {
        wRa_s[t] = re_w0_raw[t * 31 + 30];
        b0_s[t] = b0[t]; rpb_s[t] = rpb[t];
    }
    int w = t >> 6, lane = t & 63, mm = lane & 15, quad = lane >> 4;
    int colw = w * 16 + mm;                   // fixed output column of this lane
    bf16x8 W1f[4], W2f[4], WEf[4];
    #pragma unroll
    for (int kc = 0; kc < 4; kc++) {
        W1f[kc] = *(const bf16x8*)(w1b  + (size_t)colw * 128 + kc * 32 + quad * 8);
        W2f[kc] = *(const bf16x8*)(w2b  + (size_t)colw * 128 + kc * 32 + quad * 8);
        WEf[kc] = *(const bf16x8*)(wreb + (size_t)colw * 128 + kc * 32 + quad * 8);
    }
    float b1c = b1[colw], b2c = b2[colw];
    int es = t >> 3, cs2 = (t & 7) * 2;       // stage mapping: edge, chunk base
    int egs = es >> 4, ms = es & 15;
    int sseg = t >> 7, cseg = t & 127;        // segsum mapping
    int zrow = t >> 3, zc0 = (t & 7) * 16;    // coalesced Z-store mapping
    const long NT = N_E / 64;
    const long stride = gridDim.x;

    long tile = blockIdx.x;
    // prefetch first tile's gather data (Ra bits ride in edges.z)
    uint4 upC0, upC1, uqC0, uqC1; float raC; int rvC;
    {
        long nb = tile * 64;
        int4 e = edges[nb + es];
        rvC = edges[nb + (t & 63)].x;
        raC = __int_as_float(e.z);
        upC0 = *(const uint4*)(P + (size_t)e.x * 128 + (size_t)cs2 * 8);
        upC1 = *(const uint4*)(P + (size_t)e.x * 128 + (size_t)(cs2 + 1) * 8);
        uqC0 = *(const uint4*)(Q + (size_t)e.y * 128 + (size_t)cs2 * 8);
        uqC1 = *(const uint4*)(Q + (size_t)e.y * 128 + (size_t)(cs2 + 1) * 8);
    }
    __syncthreads();                           // init: wRa_s/b0_s/rpb_s visible
    int p = 0;
    for (; tile < NT; tile += stride) {
        long base = tile * 64;
        long ntile = tile + stride;
        bool hn = ntile < NT;
        // next tile: index loads (latency covered by stage+layers)
        int4 eN = make_int4(0, 0, 0, 0); int rvN = 0;
        if (hn) {
            long nb = ntile * 64;
            eN  = edges[nb + es];
            rvN = edges[nb + (t & 63)].x;
        }
        if (t < 64) rv_s[p][t] = rvC;
        // stage H1 = relu(P[rv] + Q[sv] + Ra*wRa + b0) -> BUFA (frag layout)
        {
            #pragma unroll
            for (int ci = 0; ci < 2; ci++) {
                int kq = cs2 + ci;
                uint4 up = ci ? upC1 : upC0;
                uint4 uq = ci ? uqC1 : uqC0;
                const u16* pp = (const u16*)&up; const u16* qq = (const u16*)&uq;
                u16 outv[8];
                #pragma unroll
                for (int j = 0; j < 8; j++) {
                    int c = kq * 8 + j;
                    float v = b2f(pp[j]) + b2f(qq[j]) + raC * wRa_s[c] + b0_s[c];
                    outv[j] = f2b(fmaxf(v, 0.f));
                }
                *(uint4*)&BUFA[((egs * 16 + kq) * 16 + ms) * 8] = *(uint4*)outv;
            }
        }
        bar_l();                               // bar1: BUFA + rv_s visible
        // next tile: data loads, in flight across the 4 MFMA layers
        uint4 upN0{}, upN1{}, uqN0{}, uqN1{}; float raN = 0.f;
        if (hn) {
            raN  = __int_as_float(eN.z);
            upN0 = *(const uint4*)(P + (size_t)eN.x * 128 + (size_t)cs2 * 8);
            upN1 = *(const uint4*)(P + (size_t)eN.x * 128 + (size_t)(cs2 + 1) * 8);
            uqN0 = *(const uint4*)(Q + (size_t)eN.y * 128 + (size_t)cs2 * 8);
            uqN1 = *(const uint4*)(Q + (size_t)eN.y * 128 + (size_t)(cs2 + 1) * 8);
        }
        // layer2: read A (frag), write B (frag)
        {
            f32x4 acc[4] = {};
            #pragma unroll
            for (int eg = 0; eg < 4; eg++)
                #pragma unroll
                for (int kc = 0; kc < 4; kc++) {
                    bf16x8 af = *(const bf16x8*)&BUFA[((eg * 16 + kc * 4 + quad) * 16 + mm) * 8];
                    acc[eg] = MFMA(af, W1f[kc], acc[eg]);
                }
            #pragma unroll
            for (int eg = 0; eg < 4; eg++)
                #pragma unroll
                for (int rg = 0; rg < 4; rg++)
                    BUFB[((eg * 16 + (colw >> 3)) * 16 + quad * 4 + rg) * 8 + (colw & 7)] =
                        f2b(fmaxf(acc[eg][rg] + b1c, 0.f));
        }
        bar_l();                               // bar2: B visible, A reads done
        // layer3: read B (frag), write A (frag)
        {
            f32x4 acc[4] = {};
            #pragma unroll
            for (int eg = 0; eg < 4; eg++)
                #pragma unroll
                for (int kc = 0; kc < 4; kc++) {
                    bf16x8 af = *(const bf16x8*)&BUFB[((eg * 16 + kc * 4 + quad) * 16 + mm) * 8];
                    acc[eg] = MFMA(af, W2f[kc], acc[eg]);
                }
            #pragma unroll
            for (int eg = 0; eg < 4; eg++)
                #pragma unroll
                for (int rg = 0; rg < 4; rg++)
                    BUFA[((eg * 16 + (colw >> 3)) * 16 + quad * 4 + rg) * 8 + (colw & 7)] =
                        f2b(fmaxf(acc[eg][rg] + b2c, 0.f));
        }
        bar_l();                               // bar3: A visible, B reads done
        // layer4: Z = Wre @ relenc (read A frag); raw bf16 Z -> BUFB (stride 136)
        {
            f32x4 zacc[4] = {};
            #pragma unroll
            for (int eg = 0; eg < 4; eg++)
                #pragma unroll
                for (int kc = 0; kc < 4; kc++) {
                    bf16x8 af = *(const bf16x8*)&BUFA[((eg * 16 + kc * 4 + quad) * 16 + mm) * 8];
                    zacc[eg] = MFMA(af, WEf[kc], zacc[eg]);
                }
            #pragma unroll
            for (int eg = 0; eg < 4; eg++)
                #pragma unroll
                for (int rg = 0; rg < 4; rg++)
                    BUFB[(eg * 16 + quad * 4 + rg) * 136 + colw] = f2b(zacc[eg][rg]);
        }
        bar_l();                               // bar4: raw-Z staging visible
        // coalesced non-temporal Z store: 32 contiguous bytes per thread
        {
            u32x4 z0 = *(const u32x4*)&BUFB[zrow * 136 + zc0];
            u32x4 z1 = *(const u32x4*)&BUFB[zrow * 136 + zc0 + 8];
            __builtin_nontemporal_store(z0, (u32x4*)&Z[(base + zrow) * 128 + zc0]);
            __builtin_nontemporal_store(z1, (u32x4*)&Z[(base + zrow) * 128 + zc0 + 8]);
        }
        // run-length segmented sum of relu(Z + rp_b); interior runs -> plain store
        {
            int r0 = sseg * 16;
            int cur = rv_s[p][r0];
            float a = fmaxf(b2f(BUFB[r0 * 136 + cseg]) + rpb_s[cseg], 0.f);
            bool first = true;
            for (int rr = r0 + 1; rr < r0 + 16; rr++) {
                int n = rv_s[p][rr];
                float v = fmaxf(b2f(BUFB[rr * 136 + cseg]) + rpb_s[cseg], 0.f);
                if (n == cur) a += v;
                else {
                    if (first) atomicAdd(&agg[(size_t)cur * 128 + cseg], a);
                    else       agg[(size_t)cur * 128 + cseg] = a;
                    first = false; cur = n; a = v;
                }
            }
            atomicAdd(&agg[(size_t)cur * 128 + cseg], a);
        }
        // rotate prefetched gather data
        if (hn) { upC0 = upN0; upC1 = upN1; uqC0 = uqN0; uqC1 = uqN1; raC = raN; rvC = rvN; }
        p ^= 1;
    }
}

// ================= node update step 1 (col-split, register-resident Wa/Wr/Ws) ======
// Zeroes agg in place after reading (each row read exactly once by this kernel)
// -> the second 32MB agg memset dispatch is eliminated.
__global__ __launch_bounds__(512, 4) void k_node2(
        float* __restrict__ agg, const u16* __restrict__ T,
        const u16* __restrict__ wab, const float* __restrict__ ppb,
        const u16* __restrict__ wrb, const u16* __restrict__ wsb,
        u16* __restrict__ U, u16* __restrict__ V) {
    __shared__ __align__(16) u16 BUFA[64 * 128];
    __shared__ __align__(16) u16 BUFB[64 * 128];
    int t = threadIdx.x;
    int w = t >> 6, lane = t & 63, mm = lane & 15, quad = lane >> 4;
    int colw = w * 16 + mm;
    bf16x8 WAf[4], WRf[4], WSf[4];
    #pragma unroll
    for (int kc = 0; kc < 4; kc++) {
        WAf[kc] = *(const bf16x8*)(wab + (size_t)colw * 128 + kc * 32 + quad * 8);
        WRf[kc] = *(const bf16x8*)(wrb + (size_t)colw * 128 + kc * 32 + quad * 8);
        WSf[kc] = *(const bf16x8*)(wsb + (size_t)colw * 128 + kc * 32 + quad * 8);
    }
    float ppbc = ppb[colw];
    int es = t >> 3, cs2 = (t & 7) * 2;
    int egs = es >> 4, ms = es & 15;
    const int NTL = N_P / 64;
    for (int tile = blockIdx.x; tile < NTL; tile += gridDim.x) {
        long base = (long)tile * 64;
        __syncthreads();                       // prev tile's BUFB reads done
        // stage agg -> BUFA (frag layout); zero agg behind the read
        #pragma unroll
        for (int ci = 0; ci < 2; ci++) {
            int kq = cs2 + ci;
            float* src = agg + (base + es) * 128 + kq * 8;
            float4 f0 = *(const float4*)src, f1 = *(const float4*)(src + 4);
            uint4 v;
            v.x = pk2(f0.x, f0.y); v.y = pk2(f0.z, f0.w);
            v.z = pk2(f1.x, f1.y); v.w = pk2(f1.z, f1.w);
            *(uint4*)&BUFA[((egs * 16 + kq) * 16 + ms) * 8] = v;
            float4 zz = make_float4(0.f, 0.f, 0.f, 0.f);
            *(float4*)src = zz; *(float4*)(src + 4) = zz;
        }
        bar_l();                               // BUFA visible
        // eff = relu(Wa@agg + T + ppb) -> BUFB (frag layout)
        {
            f32x4 acc[4] = {};
            #pragma unroll
            for (int eg = 0; eg < 4; eg++)
                #pragma unroll
                for (int kc = 0; kc < 4; kc++) {
                    bf16x8 af = *(const bf16x8*)&BUFA[((eg * 16 + kc * 4 + quad) * 16 + mm) * 8];
                    acc[eg] = MFMA(af, WAf[kc], acc[eg]);
                }
            #pragma unroll
            for (int eg = 0; eg < 4; eg++)
                #pragma unroll
                for (int rg = 0; rg < 4; rg++) {
                    long row = base + eg * 16 + quad * 4 + rg;
                    float v = acc[eg][rg] + b2f(T[row * 128 + colw]) + ppbc;
                    BUFB[((eg * 16 + (colw >> 3)) * 16 + quad * 4 + rg) * 8 + (colw & 7)] =
                        f2b(fmaxf(v, 0.f));
                }
        }
        bar_l();                               // BUFB visible, BUFA reads done
        // U = Wr@eff, V = Ws@eff (single pass over BUFB)
        {
            f32x4 au[4] = {}, av[4] = {};
            #pragma unroll
            for (int eg = 0; eg < 4; eg++)
                #pragma unroll
                for (int kc = 0; kc < 4; kc++) {
                    bf16x8 af = *(const bf16x8*)&BUFB[((eg * 16 + kc * 4 + quad) * 16 + mm) * 8];
                    au[eg] = MFMA(af, WRf[kc], au[eg]);
                    av[eg] = MFMA(af, WSf[kc], av[eg]);
                }
            #pragma unroll
            for (int eg = 0; eg < 4; eg++)
                #pragma unroll
                for (int rg = 0; rg < 4; rg++) {
                    long row = base + eg * 16 + quad * 4 + rg;
                    U[row * 128 + colw] = f2b(au[eg][rg]);
                    V[row * 128 + colw] = f2b(av[eg][rg]);
                }
        }
    }
}

// ================= node update step 2 (col-split) + fused fluid MLP + rigid pool ====
__global__ __launch_bounds__(512, 4) void k_node2fl(
        const float* __restrict__ agg, const u16* __restrict__ T,
        const u16* __restrict__ wab, const float* __restrict__ ppb,
        float* __restrict__ pooledsum,
        const u16* __restrict__ w0b, const float* __restrict__ b0,
        const u16* __restrict__ w1b, const float* __restrict__ b1,
        const u16* __restrict__ w2b, const float* __restrict__ b2,
        float* __restrict__ out) {
    __shared__ __align__(16) u16 BUFA[64 * 128];
    __shared__ __align__(16) u16 BUFB[64 * 128];
    int t = threadIdx.x;
    int w = t >> 6, lane = t & 63, mm = lane & 15, quad = lane >> 4;
    int colw = w * 16 + mm;
    bf16x8 WAf[4], W0f[4], W1f[4];
    #pragma unroll
    for (int kc = 0; kc < 4; kc++) {
        WAf[kc] = *(const bf16x8*)(wab + (size_t)colw * 128 + kc * 32 + quad * 8);
        W0f[kc] = *(const bf16x8*)(w0b + (size_t)colw * 128 + kc * 32 + quad * 8);
        W1f[kc] = *(const bf16x8*)(w1b + (size_t)colw * 128 + kc * 32 + quad * 8);
    }
    float ppbc = ppb[colw], b0c = b0[colw], b1c = b1[colw];
    int es = t >> 3, cs2 = (t & 7) * 2;
    int egs = es >> 4, ms = es & 15;
    const int NTL = N_P / 64;
    for (int tile = blockIdx.x; tile < NTL; tile += gridDim.x) {
        long base = (long)tile * 64;
        bool fluid = base >= RIG_;
        bar_l();                               // prev tile's BUF reads done
        // stage agg -> BUFA (frag layout)
        #pragma unroll
        for (int ci = 0; ci < 2; ci++) {
            int kq = cs2 + ci;
            const float* src = agg + (base + es) * 128 + kq * 8;
            float4 f0 = *(const float4*)src, f1 = *(const float4*)(src + 4);
            uint4 v;
            v.x = pk2(f0.x, f0.y); v.y = pk2(f0.z, f0.w);
            v.z = pk2(f1.x, f1.y); v.w = pk2(f1.z, f1.w);
            *(uint4*)&BUFA[((egs * 16 + kq) * 16 + ms) * 8] = v;
        }
        bar_l();                               // BUFA visible
        // eff = relu(Wa@agg + T + ppb)
        f32x4 acc[4] = {};
        #pragma unroll
        for (int eg = 0; eg < 4; eg++)
            #pragma unroll
            for (int kc = 0; kc < 4; kc++) {
                bf16x8 af = *(const bf16x8*)&BUFA[((eg * 16 + kc * 4 + quad) * 16 + mm) * 8];
                acc[eg] = MFMA(af, WAf[kc], acc[eg]);
            }
        if (!fluid) {
            // rigid: per-lane col partial sum over its 16 rows, reduce across quads
            float s = 0.f;
            #pragma unroll
            for (int eg = 0; eg < 4; eg++)
                #pragma unroll
                for (int rg = 0; rg < 4; rg++) {
                    long row = base + eg * 16 + quad * 4 + rg;
                    float v = acc[eg][rg] + b2f(T[row * 128 + colw]) + ppbc;
                    s += b2f(f2b(fmaxf(v, 0.f)));
                }
            s += __shfl_xor(s, 16);
            s += __shfl_xor(s, 32);
            if (quad == 0) atomicAdd(&pooledsum[colw], s);
            continue;                          // block-uniform
        }
        #pragma unroll
        for (int eg = 0; eg < 4; eg++)
            #pragma unroll
            for (int rg = 0; rg < 4; rg++) {
                long row = base + eg * 16 + quad * 4 + rg;
                float v = acc[eg][rg] + b2f(T[row * 128 + colw]) + ppbc;
                BUFB[((eg * 16 + (colw >> 3)) * 16 + quad * 4 + rg) * 8 + (colw & 7)] =
                    f2b(fmaxf(v, 0.f));
            }
        bar_l();                               // BUFB visible, BUFA reads done
        // fluid L0: BUFB -> BUFA
        {
            f32x4 a[4] = {};
            #pragma unroll
            for (int eg = 0; eg < 4; eg++)
                #pragma unroll
                for (int kc = 0; kc < 4; kc++) {
                    bf16x8 af = *(const bf16x8*)&BUFB[((eg * 16 + kc * 4 + quad) * 16 + mm) * 8];
                    a[eg] = MFMA(af, W0f[kc], a[eg]);
                }
            #pragma unroll
            for (int eg = 0; eg < 4; eg++)
                #pragma unroll
                for (int rg = 0; rg < 4; rg++)
                    BUFA[((eg * 16 + (colw >> 3)) * 16 + quad * 4 + rg) * 8 + (colw & 7)] =
                        f2b(fmaxf(a[eg][rg] + b0c, 0.f));
        }
        bar_l();                               // BUFA visible, BUFB reads done
        // fluid L1: BUFA -> BUFB
        {
            f32x4 a[4] = {};
            #pragma unroll
            for (int eg = 0; eg < 4; eg++)
                #pragma unroll
                for (int kc = 0; kc < 4; kc++) {
                    bf16x8 af = *(const bf16x8*)&BUFA[((eg * 16 + kc * 4 + quad) * 16 + mm) * 8];
                    a[eg] = MFMA(af, W1f[kc], a[eg]);
                }
            #pragma unroll
            for (int eg = 0; eg < 4; eg++)
                #pragma unroll
                for (int rg = 0; rg < 4; rg++)
                    BUFB[((eg * 16 + (colw >> 3)) * 16 + quad * 4 + rg) * 8 + (colw & 7)] =
                        f2b(fmaxf(a[eg][rg] + b1c, 0.f));
        }
        bar_l();                               // BUFB visible
        // fluid L2 -> out: waves 0-3 handle row-tiles 0-3 (w2b streamed, 4KB)
        if (w < 4) {
            f32x4 a1 = {};
            #pragma unroll
            for (int kc = 0; kc < 4; kc++) {
                bf16x8 af = *(const bf16x8*)&BUFB[((w * 16 + kc * 4 + quad) * 16 + mm) * 8];
                bf16x8 bf = *(const bf16x8*)(w2b + (size_t)mm * 128 + kc * 32 + quad * 8);
                a1 = MFMA(af, bf, a1);
            }
            if (mm < 3) {
                float bv = b2[mm];
                #pragma unroll
                for (int rg = 0; rg < 4; rg++) {
                    long row = base + w * 16 + quad * 4 + rg;
                    out[row * 3 + mm] = a1[rg] + bv;
                }
            }
        }
    }
}

// ================= step-2 edge (persistent, pipelined): relu(Z+U[rv]+V[sv]+b) -> segsum ==
// Z loads NON-TEMPORAL (streaming, read-once): keep U/V gather set L2-resident.
__global__ __launch_bounds__(512, 4) void k_edge2(
        const u16* __restrict__ Z, const u16* __restrict__ U, const u16* __restrict__ V,
        const int4* __restrict__ edges,
        const float* __restrict__ rpb, float* __restrict__ agg) {
    __shared__ __align__(16) u16 S16[2][64 * 136];
    __shared__ int rv_s[2][64];
    __shared__ float rpb_s[128];
    int t = threadIdx.x;
    if (t < 128) rpb_s[t] = rpb[t];
    int ec = t >> 3, cc = (t & 7) * 16;       // edge, col-chunk base
    int sseg = t >> 7, cseg = t & 127;        // segsum mapping (4 strips of 16)
    const long NT = N_E / 64;
    const long stride = gridDim.x;

    long tile = blockIdx.x;
    // prefetch first tile's rows
    u32x4 zC0, zC1; uint4 uC0, uC1, vC0, vC1; int rvC;
    {
        long nb = tile * 64;
        int4 e = edges[nb + ec];
        rvC = edges[nb + (t & 63)].x;
        const u16* zp = Z + (nb + ec) * 128 + cc;
        zC0 = __builtin_nontemporal_load((const u32x4*)zp);
        zC1 = __builtin_nontemporal_load((const u32x4*)(zp + 8));
        const u16* up = U + (size_t)e.x * 128 + cc;
        uC0 = *(const uint4*)up; uC1 = *(const uint4*)(up + 8);
        const u16* vp = V + (size_t)e.y * 128 + cc;
        vC0 = *(const uint4*)vp; vC1 = *(const uint4*)(vp + 8);
    }
    __syncthreads();                           // rpb_s visible
    int p = 0;
    for (; tile < NT; tile += stride) {
        long ntile = tile + stride;
        bool hn = ntile < NT;
        if (t < 64) rv_s[p][t] = rvC;
        // stage relu(z + u + v + rpb) -> S16[p] from prefetched registers
        {
            const u16* zz = (const u16*)&zC0; const u16* uu = (const u16*)&uC0;
            const u16* vv = (const u16*)&vC0;
            u16 o[8];
            #pragma unroll
            for (int j = 0; j < 8; j++)
                o[j] = f2b(fmaxf(b2f(zz[j]) + b2f(uu[j]) + b2f(vv[j]) + rpb_s[cc + j], 0.f));
            *(uint4*)&S16[p][ec * 136 + cc] = *(uint4*)o;
            zz = (const u16*)&zC1; uu = (const u16*)&uC1; vv = (const u16*)&vC1;
            #pragma unroll
            for (int j = 0; j < 8; j++)
                o[j] = f2b(fmaxf(b2f(zz[j]) + b2f(uu[j]) + b2f(vv[j]) + rpb_s[cc + 8 + j], 0.f));
            *(uint4*)&S16[p][ec * 136 + cc + 8] = *(uint4*)o;
        }
        // next tile's loads: in flight across the barrier + segsum
        u32x4 zN0{}, zN1{}; uint4 uN0{}, uN1{}, vN0{}, vN1{}; int rvN = 0;
        if (hn) {
            long nb = ntile * 64;
            int4 e = edges[nb + ec];
            rvN = edges[nb + (t & 63)].x;
            const u16* zp = Z + (nb + ec) * 128 + cc;
            zN0 = __builtin_nontemporal_load((const u32x4*)zp);
            zN1 = __builtin_nontemporal_load((const u32x4*)(zp + 8));
            const u16* up = U + (size_t)e.x * 128 + cc;
            uN0 = *(const uint4*)up; uN1 = *(const uint4*)(up + 8);
            const u16* vp = V + (size_t)e.y * 128 + cc;
            vN0 = *(const uint4*)vp; vN1 = *(const uint4*)(vp + 8);
        }
        bar_l();                               // S16[p] + rv_s[p] visible
        // run-length segmented sum; interior runs -> plain store
        {
            int r0 = sseg * 16;
            int cur = rv_s[p][r0];
            float a = b2f(S16[p][r0 * 136 + cseg]);
            bool first = true;
            for (int rr = r0 + 1; rr < r0 + 16; rr++) {
                int n = rv_s[p][rr];
                float v = b2f(S16[p][rr * 136 + cseg]);
                if (n == cur) a += v;
                else {
                    if (first) atomicAdd(&agg[(size_t)cur * 128 + cseg], a);
                    else       agg[(size_t)cur * 128 + cseg] = a;
                    first = false; cur = n; a = v;
                }
            }
            atomicAdd(&agg[(size_t)cur * 128 + cseg], a);
        }
        // rotate prefetched rows
        if (hn) { zC0 = zN0; zC1 = zN1; uC0 = uN0; uC1 = uN1; vC0 = vN0; vC1 = vN1; rvC = rvN; }
        p ^= 1;
    }
}

// ================= rigid head (pooled = sum/RIG) =================
__global__ __launch_bounds__(128) void k_rigid_head(
        const float* __restrict__ pooledsum,
        const float* __restrict__ w0, const float* __restrict__ b0,
        const float* __restrict__ w1, const float* __restrict__ b1,
        const float* __restrict__ w2, const float* __restrict__ b2,
        float* __restrict__ rig) {
    __shared__ float pl[128], ha[128], hb[128], tv[7];
    int t = threadIdx.x;
    pl[t] = pooledsum[t] * (1.0f / (float)RIG_);
    __syncthreads();
    float a = b0[t];
    for (int k = 0; k < 128; k++) a += w0[t * 128 + k] * pl[k];
    ha[t] = fmaxf(a, 0.f);
    __syncthreads();
    a = b1[t];
    for (int k = 0; k < 128; k++) a += w1[t * 128 + k] * ha[k];
    hb[t] = fmaxf(a, 0.f);
    __syncthreads();
    if (t < 7) {
        float s = b2[t];
        for (int k = 0; k < 128; k++) s += w2[t * 128 + k] * hb[k];
        tv[t] = s;
    }
    __syncthreads();
    if (t == 0) {
        float w = tv[0], x = tv[1], y = tv[2], z = tv[3];
        float n = sqrtf(w * w + x * x + y * y + z * z);
        w /= n; x /= n; y /= n; z /= n;
        rig[0] = 1.f - 2.f * (y * y + z * z); rig[1] = 2.f * (x * y + z * w); rig[2] = 2.f * (x * z - y * w);
        rig[3] = 2.f * (x * y - z * w); rig[4] = 1.f - 2.f * (x * x + z * z); rig[5] = 2.f * (y * z + x * w);
        rig[6] = 2.f * (x * z + y * w); rig[7] = 2.f * (y * z - x * w); rig[8] = 1.f - 2.f * (x * x + y * y);
        rig[9] = tv[4]; rig[10] = tv[5]; rig[11] = tv[6];
    }
}

// ================= rigid output =================
__global__ __launch_bounds__(256) void k_rigid_out(
        const float* __restrict__ state, const float* __restrict__ cent,
        const float* __restrict__ rig, float* __restrict__ out) {
    int i = blockIdx.x * 256 + threadIdx.x;
    if (i >= RIG_) return;
    float p0[3], d[3];
    #pragma unroll
    for (int k = 0; k < 3; k++) { p0[k] = state[i * 6 + k]; d[k] = p0[k] - cent[k]; }
    #pragma unroll
    for (int j = 0; j < 3; j++) {
        float p1 = rig[0 * 3 + j] * d[0] + rig[1 * 3 + j] * d[1] + rig[2 * 3 + j] * d[2]
                 + rig[9 + j] + cent[j];
        out[i * 3 + j] = (p1 - p0[j]) * 60.0f;
    }
}

// ================= host =================
extern "C" void kernel_launch(void* const* d_in, const int* in_sizes, int n_in,
                              void* d_out, int out_size, void* d_ws, size_t ws_size,
                              hipStream_t stream) {
    const float* state = (const float*)d_in[0];
    const float* attr  = (const float*)d_in[1];
    const float* Ra    = (const float*)d_in[2];
    const int*   recv  = (const int*)d_in[3];
    const int*   send  = (const int*)d_in[4];
    const float* pe_w0 = (const float*)d_in[5];  const float* pe_b0 = (const float*)d_in[6];
    const float* pe_w1 = (const float*)d_in[7];  const float* pe_b1 = (const float*)d_in[8];
    const float* re_w0 = (const float*)d_in[9];  const float* re_b0 = (const float*)d_in[10];
    const float* re_w1 = (const float*)d_in[11]; const float* re_b1 = (const float*)d_in[12];
    const float* re_w2 = (const float*)d_in[13]; const float* re_b2 = (const float*)d_in[14];
    const float* rp_w  = (const float*)d_in[15]; const float* rp_b  = (const float*)d_in[16];
    const float* pp_w  = (const float*)d_in[17]; const float* pp_b  = (const float*)d_in[18];
    const float* rg_w0 = (const float*)d_in[19]; const float* rg_b0 = (const float*)d_in[20];
    const float* rg_w1 = (const float*)d_in[21]; const float* rg_b1 = (const float*)d_in[22];
    const float* rg_w2 = (const float*)d_in[23]; const float* rg_b2 = (const float*)d_in[24];
    const float* fl_w0 = (const float*)d_in[25]; const float* fl_b0 = (const float*)d_in[26];
    const float* fl_w1 = (const float*)d_in[27]; const float* fl_b1 = (const float*)d_in[28];
    const float* fl_w2 = (const float*)d_in[29]; const float* fl_b2 = (const float*)d_in[30];
    float* out = (float*)d_out;

    // ---- workspace carve-out ----
    char* p = (char*)d_ws;
    auto alloc = [&](size_t bytes) { char* r = p; p += (bytes + 255) / 256 * 256; return r; };
    float* cent    = (float*)alloc(8 * 4);
    float* pooled  = (float*)alloc(128 * 4);
    float* rig     = (float*)alloc(16 * 4);
    u32*   rowhead = (u32*)alloc((size_t)N_P * 4);
    u32*   bsum    = (u32*)alloc(256 * 4);
    int4*  edges   = (int4*)alloc((size_t)N_E * 16);
    float* agg     = (float*)alloc((size_t)N_P * 128 * 4);
    u16*   Z       = (u16*)alloc((size_t)N_E * 128 * 2);
    u16*   T       = (u16*)alloc((size_t)N_P * 128 * 2);
    u16*   P       = (u16*)alloc((size_t)N_P * 128 * 2);   // aliased as U after k_rel
    u16*   Q       = (u16*)alloc((size_t)N_P * 128 * 2);   // aliased as V after k_rel
    u16*   wreb    = (u16*)alloc(128 * 128 * 2);
    u16*   wrb     = (u16*)alloc(128 * 128 * 2);
    u16*   wsb     = (u16*)alloc(128 * 128 * 2);
    u16*   wpb     = (u16*)alloc(128 * 128 * 2);
    u16*   wab     = (u16*)alloc(128 * 128 * 2);
    u16*   rw1b    = (u16*)alloc(128 * 128 * 2);
    u16*   rw2b    = (u16*)alloc(128 * 128 * 2);
    u16*   pew1b   = (u16*)alloc(128 * 128 * 2);
    u16*   flw0b   = (u16*)alloc(128 * 128 * 2);
    u16*   flw1b   = (u16*)alloc(128 * 128 * 2);
    u16*   flw2b   = (u16*)alloc(16 * 128 * 2);
    u16*   w0rb    = (u16*)alloc(128 * 32 * 2);
    u16*   w0sb    = (u16*)alloc(128 * 32 * 2);
    u16*   pew0b   = (u16*)alloc(128 * 32 * 2);
    size_t need = (size_t)(p - (char*)d_ws);
    if (ws_size < need) {
        fprintf(stderr, "kernel_launch: ws_size %zu < needed %zu\n", ws_size, need);
        return;
    }
    u16* U = P; u16* V = Q;

    // ---- sort edges by recv ----
    hipMemsetAsync(rowhead, 0, (size_t)N_P * 4, stream);
    k_hist<<<N_E / 256, 256, 0, stream>>>(recv, rowhead);
    k_scan1<<<N_P / 256, 256, 0, stream>>>(rowhead, bsum);
    k_scan2<<<1, 256, 0, stream>>>(bsum);
    k_scan3<<<N_P / 256, 256, 0, stream>>>(rowhead, bsum);
    k_scatter<<<N_E / 256, 256, 0, stream>>>(recv, send, Ra, rowhead, edges);

    // ---- weight conversion ----
    CvtArgs ca;
    int bs = 0;
    auto addjob = [&](int idx, const float* s, u16* d, int n, int mode) {
        ca.j[idx] = {s, d, n, mode, bs};
        bs += (n + 255) / 256;
    };
    addjob(0,  rp_w,        wreb,  128 * 128, 3);
    addjob(1,  rp_w + 128,  wrb,   128 * 128, 3);
    addjob(2,  rp_w + 256,  wsb,   128 * 128, 3);
    addjob(3,  pp_w,        wpb,   128 * 128, 4);
    addjob(4,  pp_w + 128,  wab,   128 * 128, 4);
    addjob(5,  re_w1,       rw1b,  128 * 128, 0);
    addjob(6,  re_w2,       rw2b,  128 * 128, 0);
    addjob(7,  pe_w1,       pew1b, 128 * 128, 0);
    addjob(8,  fl_w0,       flw0b, 128 * 128, 0);
    addjob(9,  fl_w1,       flw1b, 128 * 128, 0);
    addjob(10, fl_w2,       flw2b, 16 * 128,  2);
    addjob(11, re_w0,       w0rb,  128 * 32,  5);
    addjob(12, re_w0,       w0sb,  128 * 32,  6);
    addjob(13, pe_w0,       pew0b, 128 * 32,  7);
    k_cvt_all<<<bs, 256, 0, stream>>>(ca);

    // ---- encoders ----
    k_centroid<<<6, 256, 0, stream>>>(state, cent);
    k_particle_ext<<<512, 512, 0, stream>>>(state, attr, cent,
                                            w0rb, w0sb, pew0b, pe_b0,
                                            pew1b, pe_b1, wpb, P, Q, T);

    // ---- step 1: rel-enc + Z + fused agg ----
    hipMemsetAsync(agg, 0, (size_t)N_P * 128 * 4, stream);
    k_rel<<<512, 512, 0, stream>>>(P, Q, edges,
                                   re_w0, re_b0, rw1b, re_b1, rw2b, re_b2,
                                   wreb, rp_b, Z, agg);
    // node update fused with U/V production; agg zeroed in place here
    // (second 32MB memset dispatch eliminated)
    k_node2<<<512, 512, 0, stream>>>(agg, T, wab, pp_b, wrb, wsb, U, V);

    // ---- step 2 ----
    hipMemsetAsync(pooled, 0, 128 * 4, stream);
    k_edge2<<<512, 512, 0, stream>>>(Z, U, V, edges, rp_b, agg);
    // node update fused with fluid MLP + rigid pooled accumulation (col-split)
    k_node2fl<<<512, 512, 0, stream>>>(agg, T, wab, pp_b, pooled,
                                       flw0b, fl_b0, flw1b, fl_b1,
                                       flw2b, fl_b2, out);

    // ---- heads (rigid) ----
    k_rigid_head<<<1, 128, 0, stream>>>(pooled, rg_w0, rg_b0, rg_w1, rg_b1, rg_w2, rg_b2, rig);
    k_rigid_out<<<(RIG_ + 255) / 256, 256, 0, stream>>>(state, cent, rig, out);
}